// Round 2
// baseline (9312.785 us; speedup 1.0000x reference)
//
#include <hip/hip_runtime.h>

#define NN 32768      // total nodes
#define GG 256        // graphs
#define NPGN 128      // nodes per graph
#define ET 524288     // total edges
#define EH 262144     // edges per direction
#define D1 128        // input feature dim
#define D2 256        // hidden dim
#define RR 200        // relations

// ---- per-direction src-degree (segment_sum of ones over src) ----
__global__ void k_degree(const int* __restrict__ ei, float* __restrict__ deg_in,
                         float* __restrict__ deg_out) {
    int e = blockIdx.x * blockDim.x + threadIdx.x;
    if (e >= ET) return;
    if (e < EH) atomicAdd(&deg_in[ei[e]], 1.0f);
    else        atomicAdd(&deg_out[ei[e]], 1.0f);
}

// ---- norm[e] = dinv[src]*dinv[dst], dinv = deg>0 ? deg^-0.5 : 0 ----
__global__ void k_norm(const int* __restrict__ ei, const float* __restrict__ deg,
                       float* __restrict__ norm, int off) {
    int e = blockIdx.x * blockDim.x + threadIdx.x;
    if (e >= EH) return;
    int s = ei[off + e];
    int d = ei[ET + off + e];
    float ds = deg[s], dd = deg[d];
    float a = ds > 0.f ? rsqrtf(ds) : 0.f;
    float b = dd > 0.f ? rsqrtf(dd) : 0.f;
    norm[e] = a * b;
}

// ---- agg[dst] += norm * (x[src] .* rel[etype]); 4 feats per thread ----
__global__ void k_scatter(const float* __restrict__ x, const float* __restrict__ rel,
                          const int* __restrict__ ei, const int* __restrict__ et,
                          const float* __restrict__ norm, float* __restrict__ agg,
                          int off, int K, int logc) {
    int gid = blockIdx.x * blockDim.x + threadIdx.x;
    int e = gid >> logc;                 // logc = log2(K/4)
    if (e >= EH) return;
    int c = (gid & ((1 << logc) - 1)) << 2;
    int s = ei[off + e];
    int d = ei[ET + off + e];
    int t = et[off + e];
    float nm = norm[e];
    float4 xv = *(const float4*)(x + (size_t)s * K + c);
    float4 rv = *(const float4*)(rel + (size_t)t * K + c);
    float* ap = agg + (size_t)d * K + c;
    atomicAdd(ap + 0, xv.x * rv.x * nm);
    atomicAdd(ap + 1, xv.y * rv.y * nm);
    atomicAdd(ap + 2, xv.z * rv.z * nm);
    atomicAdd(ap + 3, xv.w * rv.w * nm);
}

// ---- C[M x 256] op= (A[M x K] .* rs[k]) @ W[K x 256]  (all f32) ----
// mode 0: C = acc ; mode 1: C += acc ; mode 2: C = (C + acc)/3 + bias
__global__ __launch_bounds__(256) void k_gemm(
    const float* __restrict__ A, const float* __restrict__ W,
    float* __restrict__ C, int M, int K, int mode,
    const float* __restrict__ rs, const float* __restrict__ bias) {
    __shared__ float As[16][68];  // [k][m], stride 68 keeps 16B align + breaks conflicts
    __shared__ float Ws[16][68];  // [k][n]
    const int tid = threadIdx.x;
    const int tx = tid & 15, ty = tid >> 4;
    const int arow = tid >> 2;          // 0..63
    const int akc  = (tid & 3) << 2;    // 0,4,8,12
    const int wk   = tid >> 4;          // 0..15
    const int wn0  = (tid & 15) << 2;   // 0..60
    const int rowBase = blockIdx.x << 6;
    const int colBase = blockIdx.y << 6;
    float acc[4][4] = {};
    for (int k0 = 0; k0 < K; k0 += 16) {
        float4 av = make_float4(0.f, 0.f, 0.f, 0.f);
        int r = rowBase + arow;
        if (r < M) av = *(const float4*)(A + (size_t)r * K + k0 + akc);
        if (rs) {
            av.x *= rs[k0 + akc + 0];
            av.y *= rs[k0 + akc + 1];
            av.z *= rs[k0 + akc + 2];
            av.w *= rs[k0 + akc + 3];
        }
        As[akc + 0][arow] = av.x;
        As[akc + 1][arow] = av.y;
        As[akc + 2][arow] = av.z;
        As[akc + 3][arow] = av.w;
        float4 wv = *(const float4*)(W + (size_t)(k0 + wk) * D2 + colBase + wn0);
        Ws[wk][wn0 + 0] = wv.x;
        Ws[wk][wn0 + 1] = wv.y;
        Ws[wk][wn0 + 2] = wv.z;
        Ws[wk][wn0 + 3] = wv.w;
        __syncthreads();
#pragma unroll
        for (int kk = 0; kk < 16; ++kk) {
            float a0 = As[kk][(ty << 2) + 0], a1 = As[kk][(ty << 2) + 1];
            float a2 = As[kk][(ty << 2) + 2], a3 = As[kk][(ty << 2) + 3];
            float w0 = Ws[kk][(tx << 2) + 0], w1 = Ws[kk][(tx << 2) + 1];
            float w2 = Ws[kk][(tx << 2) + 2], w3 = Ws[kk][(tx << 2) + 3];
            acc[0][0] += a0 * w0; acc[0][1] += a0 * w1; acc[0][2] += a0 * w2; acc[0][3] += a0 * w3;
            acc[1][0] += a1 * w0; acc[1][1] += a1 * w1; acc[1][2] += a1 * w2; acc[1][3] += a1 * w3;
            acc[2][0] += a2 * w0; acc[2][1] += a2 * w1; acc[2][2] += a2 * w2; acc[2][3] += a2 * w3;
            acc[3][0] += a3 * w0; acc[3][1] += a3 * w1; acc[3][2] += a3 * w2; acc[3][3] += a3 * w3;
        }
        __syncthreads();
    }
#pragma unroll
    for (int i = 0; i < 4; ++i) {
        int r = rowBase + (ty << 2) + i;
        if (r >= M) continue;
        float* cp = C + (size_t)r * D2 + colBase + (tx << 2);
        if (mode == 0) {
            cp[0] = acc[i][0]; cp[1] = acc[i][1]; cp[2] = acc[i][2]; cp[3] = acc[i][3];
        } else if (mode == 1) {
            cp[0] += acc[i][0]; cp[1] += acc[i][1]; cp[2] += acc[i][2]; cp[3] += acc[i][3];
        } else {
            int n = colBase + (tx << 2);
            cp[0] = (cp[0] + acc[i][0]) / 3.0f + bias[n + 0];
            cp[1] = (cp[1] + acc[i][1]) / 3.0f + bias[n + 1];
            cp[2] = (cp[2] + acc[i][2]) / 3.0f + bias[n + 2];
            cp[3] = (cp[3] + acc[i][3]) / 3.0f + bias[n + 3];
        }
    }
}

// ---- BN stats: sums[f] = sum, sums[256+f] = sumsq  (128 blocks x 256 rows) ----
__global__ void k_bnstats(const float* __restrict__ h, float* __restrict__ sums) {
    int f = threadIdx.x;
    const float* p = h + (size_t)blockIdx.x * 256 * 256 + f;
    float s = 0.f, q = 0.f;
#pragma unroll 8
    for (int r = 0; r < 256; ++r) {
        float v = p[(size_t)r * 256];
        s += v; q += v * v;
    }
    atomicAdd(&sums[f], s);
    atomicAdd(&sums[256 + f], q);
}

// ---- BN apply + ReLU, in place ----
__global__ void k_bnapply(float* __restrict__ h, const float* __restrict__ sums,
                          const float* __restrict__ gamma,
                          const float* __restrict__ beta) {
    int idx = blockIdx.x * blockDim.x + threadIdx.x;
    int f = idx & 255;
    float mean = sums[f] * (1.0f / NN);
    float var  = sums[256 + f] * (1.0f / NN) - mean * mean;
    float inv  = 1.0f / sqrtf(var + 1e-5f);
    float v = (h[idx] - mean) * inv * gamma[f] + beta[f];
    h[idx] = v > 0.f ? v : 0.f;
}

// ---- head features: [pooled | rel_emb[label] | h_node | t_node] per graph ----
__global__ void k_feats(const float* __restrict__ x, const float* __restrict__ rel,
                        const int* __restrict__ rel_labels, float* __restrict__ feats) {
    int g = blockIdx.x, f = threadIdx.x;
    const float* xg = x + (size_t)g * NPGN * D2;
    float s = 0.f;
#pragma unroll 8
    for (int n = 0; n < NPGN; ++n) s += xg[(size_t)n * D2 + f];
    float* fg = feats + (size_t)g * 1024;
    fg[f]       = s * (1.0f / NPGN);
    fg[256 + f] = rel[(size_t)rel_labels[g] * D2 + f];
    fg[512 + f] = xg[f];
    fg[768 + f] = xg[D2 + f];
}

// ---- final linear: out[g,c] = feats[g,:] @ lin_w + lin_b, f32 out ----
__global__ void k_head(const float* __restrict__ feats, const float* __restrict__ lw,
                       const float* __restrict__ lb, float* __restrict__ out) {
    int g = blockIdx.x, t = threadIdx.x;
    __shared__ float s0[256], s1[256];
    float a0 = 0.f, a1 = 0.f;
#pragma unroll
    for (int j = 0; j < 4; ++j) {
        int k = t * 4 + j;
        float fv = feats[(size_t)g * 1024 + k];
        a0 += fv * lw[k * 2 + 0];
        a1 += fv * lw[k * 2 + 1];
    }
    s0[t] = a0; s1[t] = a1;
    __syncthreads();
    for (int s = 128; s > 0; s >>= 1) {
        if (t < s) { s0[t] += s0[t + s]; s1[t] += s1[t + s]; }
        __syncthreads();
    }
    if (t == 0) {
        out[g * 2 + 0] = s0[0] + lb[0];
        out[g * 2 + 1] = s1[0] + lb[1];
    }
}

extern "C" void kernel_launch(void* const* d_in, const int* in_sizes, int n_in,
                              void* d_out, int out_size, void* d_ws, size_t ws_size,
                              hipStream_t stream) {
    const float* x0     = (const float*)d_in[0];   // N x 128
    const float* rel0   = (const float*)d_in[1];   // 200 x 128
    const int* edge_index = (const int*)d_in[20];
    const int* edge_type  = (const int*)d_in[21];
    const int* rel_labels = (const int*)d_in[23];
    float* out = (float*)d_out;

    float* ws = (float*)d_ws;
    float* bufA = ws;                              // N*256
    float* bufB = bufA + (size_t)NN * 256;         // N*256
    float* agg  = bufB + (size_t)NN * 256;         // N*256 (shared by both directions)
    float* relA = agg  + (size_t)NN * 256;         // 200*256
    float* relB = relA + (size_t)RR * 256;         // 200*256
    float* norm_in  = relB + (size_t)RR * 256;     // EH
    float* norm_out = norm_in + EH;                // EH
    float* bnsums   = norm_out + EH;               // 512
    float* deg_in  = agg;            // overlay: only used before first agg memset
    float* deg_out = agg + NN;
    float* feats   = agg;            // overlay: only used after last layer

    // degrees + per-edge norms (constant across layers)
    hipMemsetAsync(deg_in, 0, 2 * NN * sizeof(float), stream);
    k_degree<<<ET / 256, 256, 0, stream>>>(edge_index, deg_in, deg_out);
    k_norm<<<EH / 256, 256, 0, stream>>>(edge_index, deg_in, norm_in, 0);
    k_norm<<<EH / 256, 256, 0, stream>>>(edge_index, deg_out, norm_out, EH);

    const float* xc = x0;   float* h  = bufB;  float* xalt = bufA;
    const float* rc = rel0; float* rn = relA;  float* ralt = relB;

    for (int l = 0; l < 5; ++l) {
        const int K = (l == 0) ? D1 : D2;
        const int logc = (K == 128) ? 5 : 6;
        const float *Wi, *Wo, *Wl, *Wr, *lr, *bias, *gamma, *beta;
        if (l == 0) {
            Wi = (const float*)d_in[2];
            Wo = (const float*)d_in[3];
            Wl = (const float*)d_in[4];
            Wr = (const float*)d_in[5];
            lr = (const float*)d_in[6];
            bias  = (const float*)d_in[7];
            gamma = (const float*)d_in[8];
            beta  = (const float*)d_in[9];
        } else {
            int m = l - 1;
            Wi = (const float*)d_in[10] + (size_t)m * D2 * D2;
            Wo = (const float*)d_in[11] + (size_t)m * D2 * D2;
            Wl = (const float*)d_in[12] + (size_t)m * D2 * D2;
            Wr = (const float*)d_in[13] + (size_t)m * D2 * D2;
            lr = (const float*)d_in[14] + (size_t)m * D2;
            bias  = (const float*)d_in[15] + (size_t)m * D2;
            gamma = (const float*)d_in[16] + (size_t)m * D2;
            beta  = (const float*)d_in[17] + (size_t)m * D2;
        }
        dim3 ggrid(NN / 64, D2 / 64);
        int sblocks = EH * (K >> 2) / 256;

        // in-direction: agg = scatter, h = agg @ W_in
        hipMemsetAsync(agg, 0, (size_t)NN * K * sizeof(float), stream);
        k_scatter<<<sblocks, 256, 0, stream>>>(xc, rc, edge_index, edge_type, norm_in, agg, 0, K, logc);
        k_gemm<<<ggrid, 256, 0, stream>>>(agg, Wi, h, NN, K, 0, nullptr, nullptr);
        // out-direction: h += agg @ W_out
        hipMemsetAsync(agg, 0, (size_t)NN * K * sizeof(float), stream);
        k_scatter<<<sblocks, 256, 0, stream>>>(xc, rc, edge_index, edge_type, norm_out, agg, EH, K, logc);
        k_gemm<<<ggrid, 256, 0, stream>>>(agg, Wo, h, NN, K, 1, nullptr, nullptr);
        // self-loop: h = (h + (x .* loop_rel) @ W_loop)/3 + bias
        k_gemm<<<ggrid, 256, 0, stream>>>(xc, Wl, h, NN, K, 2, lr, bias);
        // batchnorm (batch stats) + relu
        hipMemsetAsync(bnsums, 0, 512 * sizeof(float), stream);
        k_bnstats<<<128, 256, 0, stream>>>(h, bnsums);
        k_bnapply<<<NN, 256, 0, stream>>>(h, bnsums, gamma, beta);
        // relation transform: rn = rc @ W_rel
        k_gemm<<<dim3(4, D2 / 64), 256, 0, stream>>>(rc, Wr, rn, RR, K, 0, nullptr, nullptr);

        // rotate buffers: new x = h; next h writes into the other big buffer
        const float* nx = h;
        if (l == 0) { h = bufA; xalt = bufB; }
        else { h = (float*)xc; }
        xc = nx;
        const float* nr = rn;
        if (l == 0) { rn = relB; ralt = relA; }
        else { rn = (float*)rc; }
        rc = nr;
    }

    // head
    k_feats<<<GG, 256, 0, stream>>>(xc, rc, rel_labels, feats);
    k_head<<<GG, 256, 0, stream>>>(feats, (const float*)d_in[18],
                                   (const float*)d_in[19], out);
}

// Round 3
// 1812.657 us; speedup vs baseline: 5.1376x; 5.1376x over previous
//
#include <hip/hip_runtime.h>

#define NN 32768      // total nodes
#define GG 256        // graphs
#define NPGN 128      // nodes per graph
#define ET 524288     // total directed edges
#define EH 262144     // edges per direction
#define D1 128        // input feature dim
#define D2 256        // hidden dim
#define RR 200        // relations

// ---- histograms: by-src (for norm) and by-dst (for CSR) per direction ----
__global__ void k_hist(const int* __restrict__ ei, int* __restrict__ hs_in,
                       int* __restrict__ hs_out, int* __restrict__ hd_in,
                       int* __restrict__ hd_out) {
    int e = blockIdx.x * blockDim.x + threadIdx.x;
    if (e >= ET) return;
    int s = ei[e], d = ei[ET + e];
    if (e < EH) { atomicAdd(&hs_in[s], 1);  atomicAdd(&hd_in[d], 1); }
    else        { atomicAdd(&hs_out[s], 1); atomicAdd(&hd_out[d], 1); }
}

// ---- dinv[n] = deg>0 ? deg^-0.5 : 0 (per direction, deg counted by src) ----
__global__ void k_dinv(const int* __restrict__ hs_in, const int* __restrict__ hs_out,
                       float* __restrict__ dinv_in, float* __restrict__ dinv_out) {
    int n = blockIdx.x * blockDim.x + threadIdx.x;
    if (n >= NN) return;
    int a = hs_in[n], b = hs_out[n];
    dinv_in[n]  = a > 0 ? rsqrtf((float)a) : 0.f;
    dinv_out[n] = b > 0 ? rsqrtf((float)b) : 0.f;
}

// ---- exclusive scan of 32768 ints, single block of 1024 ----
__global__ __launch_bounds__(1024) void k_scan(const int* __restrict__ hist,
                                               int* __restrict__ off) {
    __shared__ int lds[1024];
    int t = threadIdx.x;
    int base = t * 32;
    int loc[32];
    int s = 0;
#pragma unroll
    for (int i = 0; i < 32; ++i) { loc[i] = s; s += hist[base + i]; }
    lds[t] = s;
    int tot = s;
    __syncthreads();
    for (int st = 1; st < 1024; st <<= 1) {
        int v = (t >= st) ? lds[t - st] : 0;
        __syncthreads();
        lds[t] += v;
        __syncthreads();
    }
    int excl = lds[t] - tot;
#pragma unroll
    for (int i = 0; i < 32; ++i) off[base + i] = excl + loc[i];
    if (t == 1023) off[NN] = lds[1023];
}

// ---- fill CSR slots (dst-sorted); norm folded in ----
__global__ void k_fill(const int* __restrict__ ei, const int* __restrict__ et,
                       const float* __restrict__ dinv, const int* __restrict__ off,
                       int* __restrict__ cur, int* __restrict__ c_src,
                       int* __restrict__ c_et, float* __restrict__ c_norm, int eoff) {
    int e = blockIdx.x * blockDim.x + threadIdx.x;
    if (e >= EH) return;
    int s = ei[eoff + e], d = ei[ET + eoff + e], t = et[eoff + e];
    int slot = off[d] + atomicAdd(&cur[d], 1);
    c_src[slot] = s;
    c_et[slot] = t;
    c_norm[slot] = dinv[s] * dinv[d];
}

// ---- gather: one wave per dst node; agg[n] = sum_e norm*(x[src].*rel[et]) ----
template <int K>
__global__ __launch_bounds__(256) void k_gather(
    const float* __restrict__ x, const float* __restrict__ rel,
    const int* __restrict__ c_src, const int* __restrict__ c_et,
    const float* __restrict__ c_norm, const int* __restrict__ off,
    float* __restrict__ agg) {
    constexpr int VEC = K / 64;
    int node = blockIdx.x * 4 + (threadIdx.x >> 6);
    int lane = threadIdx.x & 63;
    int c = lane * VEC;
    int e0 = off[node], e1 = off[node + 1];
    float acc[VEC] = {};
    for (int e = e0; e < e1; ++e) {
        int s = c_src[e];
        int t = c_et[e];
        float nm = c_norm[e];
        const float* xp = x + (size_t)s * K + c;
        const float* rp = rel + (size_t)t * K + c;
#pragma unroll
        for (int i = 0; i < VEC; ++i) acc[i] += nm * xp[i] * rp[i];
    }
    float* ap = agg + (size_t)node * K + c;
#pragma unroll
    for (int i = 0; i < VEC; ++i) ap[i] = acc[i];
}

// ---- 2-segment GEMM: C op= A1@W1 + (A2 .* rs2)@W2 ; W row-stride = 256 ----
// mode 0: C = acc ; mode 2: C = (Cold + acc)/3 + bias
__global__ __launch_bounds__(256) void k_gemm2(
    const float* __restrict__ A1, const float* __restrict__ W1, int K1,
    const float* __restrict__ A2, const float* __restrict__ W2, int K2,
    const float* __restrict__ rs2, const float* __restrict__ bias,
    float* __restrict__ C, int M, int mode) {
    __shared__ float As[16][68];
    __shared__ float Ws[16][68];
    const int tid = threadIdx.x;
    const int tx = tid & 15, ty = tid >> 4;
    const int arow = tid >> 2;
    const int akc  = (tid & 3) << 2;
    const int wk   = tid >> 4;
    const int wn0  = (tid & 15) << 2;
    const int rowBase = blockIdx.x << 6;
    const int colBase = blockIdx.y << 6;
    float acc[4][4] = {};
    for (int seg = 0; seg < 2; ++seg) {
        const float* A = seg ? A2 : A1;
        if (!A) continue;
        const float* W = seg ? W2 : W1;
        const float* rs = seg ? rs2 : nullptr;
        const int K = seg ? K2 : K1;
        for (int k0 = 0; k0 < K; k0 += 16) {
            float4 av = make_float4(0.f, 0.f, 0.f, 0.f);
            int r = rowBase + arow;
            if (r < M) av = *(const float4*)(A + (size_t)r * K + k0 + akc);
            if (rs) {
                av.x *= rs[k0 + akc + 0];
                av.y *= rs[k0 + akc + 1];
                av.z *= rs[k0 + akc + 2];
                av.w *= rs[k0 + akc + 3];
            }
            As[akc + 0][arow] = av.x;
            As[akc + 1][arow] = av.y;
            As[akc + 2][arow] = av.z;
            As[akc + 3][arow] = av.w;
            float4 wv = *(const float4*)(W + (size_t)(k0 + wk) * D2 + colBase + wn0);
            Ws[wk][wn0 + 0] = wv.x;
            Ws[wk][wn0 + 1] = wv.y;
            Ws[wk][wn0 + 2] = wv.z;
            Ws[wk][wn0 + 3] = wv.w;
            __syncthreads();
#pragma unroll
            for (int kk = 0; kk < 16; ++kk) {
                float a0 = As[kk][(ty << 2) + 0], a1 = As[kk][(ty << 2) + 1];
                float a2 = As[kk][(ty << 2) + 2], a3 = As[kk][(ty << 2) + 3];
                float w0 = Ws[kk][(tx << 2) + 0], w1 = Ws[kk][(tx << 2) + 1];
                float w2 = Ws[kk][(tx << 2) + 2], w3 = Ws[kk][(tx << 2) + 3];
                acc[0][0] += a0 * w0; acc[0][1] += a0 * w1; acc[0][2] += a0 * w2; acc[0][3] += a0 * w3;
                acc[1][0] += a1 * w0; acc[1][1] += a1 * w1; acc[1][2] += a1 * w2; acc[1][3] += a1 * w3;
                acc[2][0] += a2 * w0; acc[2][1] += a2 * w1; acc[2][2] += a2 * w2; acc[2][3] += a2 * w3;
                acc[3][0] += a3 * w0; acc[3][1] += a3 * w1; acc[3][2] += a3 * w2; acc[3][3] += a3 * w3;
            }
            __syncthreads();
        }
    }
#pragma unroll
    for (int i = 0; i < 4; ++i) {
        int r = rowBase + (ty << 2) + i;
        if (r >= M) continue;
        float* cp = C + (size_t)r * D2 + colBase + (tx << 2);
        if (mode == 0) {
            cp[0] = acc[i][0]; cp[1] = acc[i][1]; cp[2] = acc[i][2]; cp[3] = acc[i][3];
        } else {
            int n = colBase + (tx << 2);
            cp[0] = (cp[0] + acc[i][0]) / 3.0f + bias[n + 0];
            cp[1] = (cp[1] + acc[i][1]) / 3.0f + bias[n + 1];
            cp[2] = (cp[2] + acc[i][2]) / 3.0f + bias[n + 2];
            cp[3] = (cp[3] + acc[i][3]) / 3.0f + bias[n + 3];
        }
    }
}

// ---- BN stats ----
__global__ void k_bnstats(const float* __restrict__ h, float* __restrict__ sums) {
    int f = threadIdx.x;
    const float* p = h + (size_t)blockIdx.x * 256 * 256 + f;
    float s = 0.f, q = 0.f;
#pragma unroll 8
    for (int r = 0; r < 256; ++r) {
        float v = p[(size_t)r * 256];
        s += v; q += v * v;
    }
    atomicAdd(&sums[f], s);
    atomicAdd(&sums[256 + f], q);
}

// ---- BN apply + ReLU, in place ----
__global__ void k_bnapply(float* __restrict__ h, const float* __restrict__ sums,
                          const float* __restrict__ gamma, const float* __restrict__ beta) {
    int idx = blockIdx.x * blockDim.x + threadIdx.x;
    int f = idx & 255;
    float mean = sums[f] * (1.0f / NN);
    float var  = sums[256 + f] * (1.0f / NN) - mean * mean;
    float inv  = 1.0f / sqrtf(var + 1e-5f);
    float v = (h[idx] - mean) * inv * gamma[f] + beta[f];
    h[idx] = v > 0.f ? v : 0.f;
}

// ---- head features ----
__global__ void k_feats(const float* __restrict__ x, const float* __restrict__ rel,
                        const int* __restrict__ rel_labels, float* __restrict__ feats) {
    int g = blockIdx.x, f = threadIdx.x;
    const float* xg = x + (size_t)g * NPGN * D2;
    float s = 0.f;
#pragma unroll 8
    for (int n = 0; n < NPGN; ++n) s += xg[(size_t)n * D2 + f];
    float* fg = feats + (size_t)g * 1024;
    fg[f]       = s * (1.0f / NPGN);
    fg[256 + f] = rel[(size_t)rel_labels[g] * D2 + f];
    fg[512 + f] = xg[f];
    fg[768 + f] = xg[D2 + f];
}

// ---- final linear ----
__global__ void k_head(const float* __restrict__ feats, const float* __restrict__ lw,
                       const float* __restrict__ lb, float* __restrict__ out) {
    int g = blockIdx.x, t = threadIdx.x;
    __shared__ float s0[256], s1[256];
    float a0 = 0.f, a1 = 0.f;
#pragma unroll
    for (int j = 0; j < 4; ++j) {
        int k = t * 4 + j;
        float fv = feats[(size_t)g * 1024 + k];
        a0 += fv * lw[k * 2 + 0];
        a1 += fv * lw[k * 2 + 1];
    }
    s0[t] = a0; s1[t] = a1;
    __syncthreads();
    for (int s = 128; s > 0; s >>= 1) {
        if (t < s) { s0[t] += s0[t + s]; s1[t] += s1[t + s]; }
        __syncthreads();
    }
    if (t == 0) {
        out[g * 2 + 0] = s0[0] + lb[0];
        out[g * 2 + 1] = s1[0] + lb[1];
    }
}

extern "C" void kernel_launch(void* const* d_in, const int* in_sizes, int n_in,
                              void* d_out, int out_size, void* d_ws, size_t ws_size,
                              hipStream_t stream) {
    const float* x0   = (const float*)d_in[0];
    const float* rel0 = (const float*)d_in[1];
    const int* edge_index = (const int*)d_in[20];
    const int* edge_type  = (const int*)d_in[21];
    const int* rel_labels = (const int*)d_in[23];
    float* out = (float*)d_out;

    // ---- workspace carve (~109 MB) ----
    float* ws = (float*)d_ws;
    float* bufA = ws;                               // NN*256
    float* bufB = bufA + (size_t)NN * 256;          // NN*256
    float* agg  = bufB + (size_t)NN * 256;          // NN*256
    float* relA = agg  + (size_t)NN * 256;          // RR*256
    float* relB = relA + (size_t)RR * 256;          // RR*256
    float* dinv_in  = relB + (size_t)RR * 256;      // NN
    float* dinv_out = dinv_in + NN;                 // NN
    float* cnorm_in  = dinv_out + NN;               // EH
    float* cnorm_out = cnorm_in + EH;               // EH
    float* bnsums    = cnorm_out + EH;              // 512
    int* csrc_in  = (int*)(bnsums + 512);           // EH
    int* cet_in   = csrc_in + EH;                   // EH
    int* csrc_out = cet_in + EH;                    // EH
    int* cet_out  = csrc_out + EH;                  // EH
    int* off_in   = cet_out + EH;                   // NN+1
    int* off_out  = off_in + NN + 1;                // NN+1
    int* hs_in    = off_out + NN + 1;               // NN  -- start of zeroed region
    int* hs_out   = hs_in + NN;                     // NN
    int* hd_in    = hs_out + NN;                    // NN
    int* hd_out   = hd_in + NN;                     // NN
    int* cur_in   = hd_out + NN;                    // NN
    int* cur_out  = cur_in + NN;                    // NN
    float* feats  = agg;                            // overlay after last layer

    // ---- CSR build (once per launch; reused by all 5 layers) ----
    hipMemsetAsync(hs_in, 0, 6 * NN * sizeof(int), stream);
    k_hist<<<ET / 256, 256, 0, stream>>>(edge_index, hs_in, hs_out, hd_in, hd_out);
    k_dinv<<<NN / 256, 256, 0, stream>>>(hs_in, hs_out, dinv_in, dinv_out);
    k_scan<<<1, 1024, 0, stream>>>(hd_in, off_in);
    k_scan<<<1, 1024, 0, stream>>>(hd_out, off_out);
    k_fill<<<EH / 256, 256, 0, stream>>>(edge_index, edge_type, dinv_in, off_in,
                                         cur_in, csrc_in, cet_in, cnorm_in, 0);
    k_fill<<<EH / 256, 256, 0, stream>>>(edge_index, edge_type, dinv_out, off_out,
                                         cur_out, csrc_out, cet_out, cnorm_out, EH);

    const float* xc = x0;   float* h  = bufA;
    const float* rc = rel0; float* rn = relA;

    for (int l = 0; l < 5; ++l) {
        const int K = (l == 0) ? D1 : D2;
        const float *Wi, *Wo, *Wl, *Wr, *lr, *bias, *gamma, *beta;
        if (l == 0) {
            Wi = (const float*)d_in[2];  Wo = (const float*)d_in[3];
            Wl = (const float*)d_in[4];  Wr = (const float*)d_in[5];
            lr = (const float*)d_in[6];  bias  = (const float*)d_in[7];
            gamma = (const float*)d_in[8]; beta = (const float*)d_in[9];
        } else {
            int m = l - 1;
            Wi = (const float*)d_in[10] + (size_t)m * D2 * D2;
            Wo = (const float*)d_in[11] + (size_t)m * D2 * D2;
            Wl = (const float*)d_in[12] + (size_t)m * D2 * D2;
            Wr = (const float*)d_in[13] + (size_t)m * D2 * D2;
            lr = (const float*)d_in[14] + (size_t)m * D2;
            bias  = (const float*)d_in[15] + (size_t)m * D2;
            gamma = (const float*)d_in[16] + (size_t)m * D2;
            beta  = (const float*)d_in[17] + (size_t)m * D2;
        }
        dim3 ggrid(NN / 64, D2 / 64);

        // in-direction gather + GEMM: h = agg_in @ Wi
        if (K == D1) k_gather<D1><<<NN / 4, 256, 0, stream>>>(xc, rc, csrc_in, cet_in, cnorm_in, off_in, agg);
        else         k_gather<D2><<<NN / 4, 256, 0, stream>>>(xc, rc, csrc_in, cet_in, cnorm_in, off_in, agg);
        k_gemm2<<<ggrid, 256, 0, stream>>>(agg, Wi, K, nullptr, nullptr, 0, nullptr,
                                           nullptr, h, NN, 0);
        // out-direction gather + fused GEMM: h = (h + agg_out@Wo + (xc.*lr)@Wl)/3 + bias
        if (K == D1) k_gather<D1><<<NN / 4, 256, 0, stream>>>(xc, rc, csrc_out, cet_out, cnorm_out, off_out, agg);
        else         k_gather<D2><<<NN / 4, 256, 0, stream>>>(xc, rc, csrc_out, cet_out, cnorm_out, off_out, agg);
        k_gemm2<<<ggrid, 256, 0, stream>>>(agg, Wo, K, xc, Wl, K, lr, bias, h, NN, 2);
        // batchnorm + relu
        hipMemsetAsync(bnsums, 0, 512 * sizeof(float), stream);
        k_bnstats<<<128, 256, 0, stream>>>(h, bnsums);
        k_bnapply<<<NN, 256, 0, stream>>>(h, bnsums, gamma, beta);
        // relation transform
        k_gemm2<<<dim3(4, D2 / 64), 256, 0, stream>>>(rc, Wr, K, nullptr, nullptr, 0,
                                                      nullptr, nullptr, rn, RR, 0);
        // rotate
        const float* nx = h;
        h = (l == 0) ? bufB : (float*)xc;
        xc = nx;
        const float* nr = rn;
        rn = (l == 0) ? relB : (float*)rc;
        rc = nr;
    }

    k_feats<<<GG, 256, 0, stream>>>(xc, rc, rel_labels, feats);
    k_head<<<GG, 256, 0, stream>>>(feats, (const float*)d_in[18],
                                   (const float*)d_in[19], out);
}

// Round 4
// 1059.639 us; speedup vs baseline: 8.7886x; 1.7106x over previous
//
#include <hip/hip_runtime.h>

#define NN 32768      // total nodes
#define GG 256        // graphs
#define NPGN 128      // nodes per graph
#define ET 524288     // total directed edges
#define EH 262144     // edges per direction
#define D1 128        // input feature dim
#define D2 256        // hidden dim
#define RR 200        // relations

typedef unsigned short u16;
typedef __attribute__((ext_vector_type(8))) short bf16x8;   // 4 VGPRs: MFMA A/B frag
typedef __attribute__((ext_vector_type(4))) float f32x4;    // MFMA C/D frag

__device__ __forceinline__ float bf2f(u16 u) {
    union { unsigned int i; float f; } v; v.i = ((unsigned int)u) << 16; return v.f;
}
__device__ __forceinline__ u16 f2bf(float f) {
    union { unsigned int i; float f; } v; v.f = f;
    unsigned int x = v.i;
    return (u16)((x + 0x7fffu + ((x >> 16) & 1u)) >> 16);   // RNE
}

// ---- histograms: by-src (for norm) and by-dst (for CSR) per direction ----
__global__ void k_hist(const int* __restrict__ ei, int* __restrict__ hs_in,
                       int* __restrict__ hs_out, int* __restrict__ hd_in,
                       int* __restrict__ hd_out) {
    int e = blockIdx.x * blockDim.x + threadIdx.x;
    if (e >= ET) return;
    int s = ei[e], d = ei[ET + e];
    if (e < EH) { atomicAdd(&hs_in[s], 1);  atomicAdd(&hd_in[d], 1); }
    else        { atomicAdd(&hs_out[s], 1); atomicAdd(&hd_out[d], 1); }
}

__global__ void k_dinv(const int* __restrict__ hs_in, const int* __restrict__ hs_out,
                       float* __restrict__ dinv_in, float* __restrict__ dinv_out) {
    int n = blockIdx.x * blockDim.x + threadIdx.x;
    if (n >= NN) return;
    int a = hs_in[n], b = hs_out[n];
    dinv_in[n]  = a > 0 ? rsqrtf((float)a) : 0.f;
    dinv_out[n] = b > 0 ? rsqrtf((float)b) : 0.f;
}

// ---- exclusive scan of 32768 ints, single block of 1024 ----
__global__ __launch_bounds__(1024) void k_scan(const int* __restrict__ hist,
                                               int* __restrict__ off) {
    __shared__ int lds[1024];
    int t = threadIdx.x;
    int base = t * 32;
    int loc[32];
    int s = 0;
#pragma unroll
    for (int i = 0; i < 32; ++i) { loc[i] = s; s += hist[base + i]; }
    lds[t] = s;
    int tot = s;
    __syncthreads();
    for (int st = 1; st < 1024; st <<= 1) {
        int v = (t >= st) ? lds[t - st] : 0;
        __syncthreads();
        lds[t] += v;
        __syncthreads();
    }
    int excl = lds[t] - tot;
#pragma unroll
    for (int i = 0; i < 32; ++i) off[base + i] = excl + loc[i];
    if (t == 1023) off[NN] = lds[1023];
}

// ---- fill CSR slots (dst-sorted); norm folded in ----
__global__ void k_fill(const int* __restrict__ ei, const int* __restrict__ et,
                       const float* __restrict__ dinv, const int* __restrict__ off,
                       int* __restrict__ cur, int* __restrict__ c_src,
                       int* __restrict__ c_et, float* __restrict__ c_norm, int eoff) {
    int e = blockIdx.x * blockDim.x + threadIdx.x;
    if (e >= EH) return;
    int s = ei[eoff + e], d = ei[ET + eoff + e], t = et[eoff + e];
    int slot = off[d] + atomicAdd(&cur[d], 1);
    c_src[slot] = s;
    c_et[slot] = t;
    c_norm[slot] = dinv[s] * dinv[d];
}

// ---- x0 f32 -> bf16 ----
__global__ void k_convx(const float* __restrict__ in, u16* __restrict__ out, int n) {
    int i = blockIdx.x * blockDim.x + threadIdx.x;
    if (i < n) out[i] = f2bf(in[i]);
}

// ---- weight prep: Wt[l][n][k] = bf16(W[l][k][n]), lr folded into loop family ----
__global__ void k_prepw(const float* __restrict__ Wi, const float* __restrict__ Wo,
                        const float* __restrict__ Wl, const float* __restrict__ lr,
                        u16* __restrict__ WiT, u16* __restrict__ WoT,
                        u16* __restrict__ WlT, int K, int L) {
    int idx = blockIdx.x * blockDim.x + threadIdx.x;
    int per = L * K * 256;
    if (idx >= 3 * per) return;
    int fam = idx / per, rem = idx % per;
    int l = rem / (K * 256), rr = rem % (K * 256);
    int k = rr / 256, n = rr % 256;
    const float* src = fam == 0 ? Wi : fam == 1 ? Wo : Wl;
    float v = src[((size_t)l * K + k) * 256 + n];
    if (fam == 2) v *= lr[l * K + k];
    u16* dst = fam == 0 ? WiT : fam == 1 ? WoT : WlT;
    dst[((size_t)l * 256 + n) * K + k] = f2bf(v);
}

// ---- gather: one wave per dst node; agg[n] = bf16( sum_e norm*(x[src].*rel[et]) ) ----
template <int K>
__global__ __launch_bounds__(256) void k_gather(
    const u16* __restrict__ x, const float* __restrict__ rel,
    const int* __restrict__ c_src, const int* __restrict__ c_et,
    const float* __restrict__ c_norm, const int* __restrict__ off,
    u16* __restrict__ agg) {
    constexpr int VEC = K / 64;
    int node = blockIdx.x * 4 + (threadIdx.x >> 6);
    int lane = threadIdx.x & 63;
    int c = lane * VEC;
    int e0 = off[node], e1 = off[node + 1];
    float acc[VEC] = {};
    for (int e = e0; e < e1; ++e) {
        int s = c_src[e];
        int t = c_et[e];
        float nm = c_norm[e];
        const u16* xp = x + (size_t)s * K + c;
        const float* rp = rel + (size_t)t * K + c;
        if constexpr (VEC == 4) {
            ushort4 xv = *(const ushort4*)xp;
            float4 rv = *(const float4*)rp;
            acc[0] += nm * bf2f(xv.x) * rv.x;
            acc[1] += nm * bf2f(xv.y) * rv.y;
            acc[2] += nm * bf2f(xv.z) * rv.z;
            acc[3] += nm * bf2f(xv.w) * rv.w;
        } else {
            ushort2 xv = *(const ushort2*)xp;
            float2 rv = *(const float2*)rp;
            acc[0] += nm * bf2f(xv.x) * rv.x;
            acc[1] += nm * bf2f(xv.y) * rv.y;
        }
    }
    u16* ap = agg + (size_t)node * K + c;
    if constexpr (VEC == 4) {
        ushort4 o; o.x = f2bf(acc[0]); o.y = f2bf(acc[1]); o.z = f2bf(acc[2]); o.w = f2bf(acc[3]);
        *(ushort4*)ap = o;
    } else {
        ushort2 o; o.x = f2bf(acc[0]); o.y = f2bf(acc[1]);
        *(ushort2*)ap = o;
    }
}

// ---- fused 3-segment MFMA GEMM: C = (A1@W1t + A2@W2t + A3@W3t)/3 + bias ----
// A: [NN][K] bf16 row-major; Wt: [256][K] bf16 (pre-transposed, lr pre-folded).
// Block 256 thr = 4 waves, tile 128x128; wave = 64x64 via 4x4 mfma_16x16x32.
template <int K>
__global__ __launch_bounds__(256) void k_gemm_mfma(
    const u16* __restrict__ A1, const u16* __restrict__ A2, const u16* __restrict__ A3,
    const u16* __restrict__ W1, const u16* __restrict__ W2, const u16* __restrict__ W3,
    const float* __restrict__ bias, float* __restrict__ C) {
    const int tid = threadIdx.x;
    const int wave = tid >> 6, lane = tid & 63;
    const int q = lane >> 4, r = lane & 15;
    const int rowBase = blockIdx.x * 128 + (wave & 1) * 64;
    const int colBase = blockIdx.y * 128 + (wave >> 1) * 64;
    f32x4 zero = {0.f, 0.f, 0.f, 0.f};
    f32x4 acc[4][4];
#pragma unroll
    for (int i = 0; i < 4; ++i)
#pragma unroll
        for (int j = 0; j < 4; ++j) acc[i][j] = zero;

    const u16* As[3] = {A1, A2, A3};
    const u16* Ws[3] = {W1, W2, W3};
#pragma unroll
    for (int s = 0; s < 3; ++s) {
        const u16* A = As[s];
        const u16* W = Ws[s];
        for (int k0 = 0; k0 < K; k0 += 32) {
            int ka = k0 + q * 8;
            bf16x8 a[4], b[4];
#pragma unroll
            for (int tm = 0; tm < 4; ++tm)
                a[tm] = *(const bf16x8*)(A + (size_t)(rowBase + tm * 16 + r) * K + ka);
#pragma unroll
            for (int tn = 0; tn < 4; ++tn)
                b[tn] = *(const bf16x8*)(W + (size_t)(colBase + tn * 16 + r) * K + ka);
#pragma unroll
            for (int tm = 0; tm < 4; ++tm)
#pragma unroll
                for (int tn = 0; tn < 4; ++tn)
                    acc[tm][tn] = __builtin_amdgcn_mfma_f32_16x16x32_bf16(
                        a[tm], b[tn], acc[tm][tn], 0, 0, 0);
        }
    }
#pragma unroll
    for (int tn = 0; tn < 4; ++tn) {
        int col = colBase + tn * 16 + r;
        float bv = bias[col];
#pragma unroll
        for (int tm = 0; tm < 4; ++tm) {
#pragma unroll
            for (int reg = 0; reg < 4; ++reg) {
                int row = rowBase + tm * 16 + q * 4 + reg;
                C[(size_t)row * 256 + col] = acc[tm][tn][reg] / 3.0f + bv;
            }
        }
    }
}

// ---- small f32 GEMM for the relation chain: C = A @ W  (W row-stride 256) ----
__global__ __launch_bounds__(256) void k_gemm_rel(
    const float* __restrict__ A, const float* __restrict__ W,
    float* __restrict__ C, int M, int K) {
    __shared__ float As[16][68];
    __shared__ float Ws[16][68];
    const int tid = threadIdx.x;
    const int tx = tid & 15, ty = tid >> 4;
    const int arow = tid >> 2;
    const int akc  = (tid & 3) << 2;
    const int wk   = tid >> 4;
    const int wn0  = (tid & 15) << 2;
    const int rowBase = blockIdx.x << 6;
    const int colBase = blockIdx.y << 6;
    float acc[4][4] = {};
    for (int k0 = 0; k0 < K; k0 += 16) {
        float4 av = make_float4(0.f, 0.f, 0.f, 0.f);
        int rr = rowBase + arow;
        if (rr < M) av = *(const float4*)(A + (size_t)rr * K + k0 + akc);
        As[akc + 0][arow] = av.x;
        As[akc + 1][arow] = av.y;
        As[akc + 2][arow] = av.z;
        As[akc + 3][arow] = av.w;
        float4 wv = *(const float4*)(W + (size_t)(k0 + wk) * D2 + colBase + wn0);
        Ws[wk][wn0 + 0] = wv.x;
        Ws[wk][wn0 + 1] = wv.y;
        Ws[wk][wn0 + 2] = wv.z;
        Ws[wk][wn0 + 3] = wv.w;
        __syncthreads();
#pragma unroll
        for (int kk = 0; kk < 16; ++kk) {
            float a0 = As[kk][(ty << 2) + 0], a1 = As[kk][(ty << 2) + 1];
            float a2 = As[kk][(ty << 2) + 2], a3 = As[kk][(ty << 2) + 3];
            float w0 = Ws[kk][(tx << 2) + 0], w1 = Ws[kk][(tx << 2) + 1];
            float w2 = Ws[kk][(tx << 2) + 2], w3 = Ws[kk][(tx << 2) + 3];
            acc[0][0] += a0 * w0; acc[0][1] += a0 * w1; acc[0][2] += a0 * w2; acc[0][3] += a0 * w3;
            acc[1][0] += a1 * w0; acc[1][1] += a1 * w1; acc[1][2] += a1 * w2; acc[1][3] += a1 * w3;
            acc[2][0] += a2 * w0; acc[2][1] += a2 * w1; acc[2][2] += a2 * w2; acc[2][3] += a2 * w3;
            acc[3][0] += a3 * w0; acc[3][1] += a3 * w1; acc[3][2] += a3 * w2; acc[3][3] += a3 * w3;
        }
        __syncthreads();
    }
#pragma unroll
    for (int i = 0; i < 4; ++i) {
        int rr = rowBase + (ty << 2) + i;
        if (rr >= M) continue;
        float* cp = C + (size_t)rr * D2 + colBase + (tx << 2);
        cp[0] = acc[i][0]; cp[1] = acc[i][1]; cp[2] = acc[i][2]; cp[3] = acc[i][3];
    }
}

// ---- BN stats ----
__global__ void k_bnstats(const float* __restrict__ h, float* __restrict__ sums) {
    int f = threadIdx.x;
    const float* p = h + (size_t)blockIdx.x * 256 * 256 + f;
    float s = 0.f, q = 0.f;
#pragma unroll 8
    for (int r = 0; r < 256; ++r) {
        float v = p[(size_t)r * 256];
        s += v; q += v * v;
    }
    atomicAdd(&sums[f], s);
    atomicAdd(&sums[256 + f], q);
}

// ---- BN apply + ReLU, emit bf16 x ----
__global__ void k_bnapply(const float* __restrict__ h, const float* __restrict__ sums,
                          const float* __restrict__ gamma, const float* __restrict__ beta,
                          u16* __restrict__ xb) {
    int idx = blockIdx.x * blockDim.x + threadIdx.x;
    int f = idx & 255;
    float mean = sums[f] * (1.0f / NN);
    float var  = sums[256 + f] * (1.0f / NN) - mean * mean;
    float inv  = 1.0f / sqrtf(var + 1e-5f);
    float v = (h[idx] - mean) * inv * gamma[f] + beta[f];
    xb[idx] = f2bf(v > 0.f ? v : 0.f);
}

// ---- head features ----
__global__ void k_feats(const u16* __restrict__ x, const float* __restrict__ rel,
                        const int* __restrict__ rel_labels, float* __restrict__ feats) {
    int g = blockIdx.x, f = threadIdx.x;
    const u16* xg = x + (size_t)g * NPGN * D2;
    float s = 0.f;
#pragma unroll 8
    for (int n = 0; n < NPGN; ++n) s += bf2f(xg[(size_t)n * D2 + f]);
    float* fg = feats + (size_t)g * 1024;
    fg[f]       = s * (1.0f / NPGN);
    fg[256 + f] = rel[(size_t)rel_labels[g] * D2 + f];
    fg[512 + f] = bf2f(xg[f]);
    fg[768 + f] = bf2f(xg[D2 + f]);
}

// ---- final linear ----
__global__ void k_head(const float* __restrict__ feats, const float* __restrict__ lw,
                       const float* __restrict__ lb, float* __restrict__ out) {
    int g = blockIdx.x, t = threadIdx.x;
    __shared__ float s0[256], s1[256];
    float a0 = 0.f, a1 = 0.f;
#pragma unroll
    for (int j = 0; j < 4; ++j) {
        int k = t * 4 + j;
        float fv = feats[(size_t)g * 1024 + k];
        a0 += fv * lw[k * 2 + 0];
        a1 += fv * lw[k * 2 + 1];
    }
    s0[t] = a0; s1[t] = a1;
    __syncthreads();
    for (int s = 128; s > 0; s >>= 1) {
        if (t < s) { s0[t] += s0[t + s]; s1[t] += s1[t + s]; }
        __syncthreads();
    }
    if (t == 0) {
        out[g * 2 + 0] = s0[0] + lb[0];
        out[g * 2 + 1] = s1[0] + lb[1];
    }
}

extern "C" void kernel_launch(void* const* d_in, const int* in_sizes, int n_in,
                              void* d_out, int out_size, void* d_ws, size_t ws_size,
                              hipStream_t stream) {
    const float* x0   = (const float*)d_in[0];
    const float* rel0 = (const float*)d_in[1];
    const int* edge_index = (const int*)d_in[20];
    const int* edge_type  = (const int*)d_in[21];
    const int* rel_labels = (const int*)d_in[23];
    float* out = (float*)d_out;

    // ---- workspace carve (~103 MB) ----
    float* ws = (float*)d_ws;
    float* h     = ws;                              // NN*256 f32
    float* relA  = h + (size_t)NN * 256;            // RR*256
    float* relB  = relA + (size_t)RR * 256;         // RR*256
    float* dinv_in  = relB + (size_t)RR * 256;      // NN
    float* dinv_out = dinv_in + NN;                 // NN
    float* cnorm_in  = dinv_out + NN;               // EH
    float* cnorm_out = cnorm_in + EH;               // EH
    float* bnsums    = cnorm_out + EH;              // 512
    float* feats     = bnsums + 512;                // GG*1024
    int* csrc_in  = (int*)(feats + GG * 1024);      // EH
    int* cet_in   = csrc_in + EH;                   // EH
    int* csrc_out = cet_in + EH;                    // EH
    int* cet_out  = csrc_out + EH;                  // EH
    int* off_in   = cet_out + EH;                   // NN+8 (padded for alignment)
    int* off_out  = off_in + NN + 8;                // NN+8
    int* hs_in    = off_out + NN + 8;               // NN  -- start of zeroed region
    int* hs_out   = hs_in + NN;                     // NN
    int* hd_in    = hs_out + NN;                    // NN
    int* hd_out   = hd_in + NN;                     // NN
    int* cur_in   = hd_out + NN;                    // NN
    int* cur_out  = cur_in + NN;                    // NN
    u16* xbf0 = (u16*)(cur_out + NN);               // NN*128 bf16
    u16* xbfA = xbf0 + (size_t)NN * 128;            // NN*256 bf16
    u16* aggI = xbfA + (size_t)NN * 256;            // NN*256 bf16
    u16* aggO = aggI + (size_t)NN * 256;            // NN*256 bf16
    u16* wt0  = aggO + (size_t)NN * 256;            // 3*256*128 (layer0 Wt)
    u16* wtS  = wt0 + 3 * 256 * 128;                // 12*256*256 (layers1-4 Wt)

    // ---- CSR build + weight prep (once per launch) ----
    hipMemsetAsync(hs_in, 0, 6 * NN * sizeof(int), stream);
    k_hist<<<ET / 256, 256, 0, stream>>>(edge_index, hs_in, hs_out, hd_in, hd_out);
    k_dinv<<<NN / 256, 256, 0, stream>>>(hs_in, hs_out, dinv_in, dinv_out);
    k_scan<<<1, 1024, 0, stream>>>(hd_in, off_in);
    k_scan<<<1, 1024, 0, stream>>>(hd_out, off_out);
    k_fill<<<EH / 256, 256, 0, stream>>>(edge_index, edge_type, dinv_in, off_in,
                                         cur_in, csrc_in, cet_in, cnorm_in, 0);
    k_fill<<<EH / 256, 256, 0, stream>>>(edge_index, edge_type, dinv_out, off_out,
                                         cur_out, csrc_out, cet_out, cnorm_out, EH);
    k_convx<<<(NN * D1) / 256, 256, 0, stream>>>(x0, xbf0, NN * D1);
    k_prepw<<<(3 * D1 * 256) / 256, 256, 0, stream>>>(
        (const float*)d_in[2], (const float*)d_in[3], (const float*)d_in[4],
        (const float*)d_in[6], wt0, wt0 + 256 * D1, wt0 + 2 * 256 * D1, D1, 1);
    k_prepw<<<(3 * 4 * D2 * 256) / 256, 256, 0, stream>>>(
        (const float*)d_in[10], (const float*)d_in[11], (const float*)d_in[12],
        (const float*)d_in[14], wtS, wtS + 4 * 65536, wtS + 8 * 65536, D2, 4);

    const float* rc = rel0; float* rn = relA;

    for (int l = 0; l < 5; ++l) {
        const int K = (l == 0) ? D1 : D2;
        const u16* xb = (l == 0) ? xbf0 : xbfA;
        const u16 *WiT, *WoT, *WlT;
        const float *Wr, *bias, *gamma, *beta;
        if (l == 0) {
            WiT = wt0; WoT = wt0 + 256 * D1; WlT = wt0 + 2 * 256 * D1;
            Wr = (const float*)d_in[5];
            bias  = (const float*)d_in[7];
            gamma = (const float*)d_in[8];
            beta  = (const float*)d_in[9];
        } else {
            int m = l - 1;
            WiT = wtS + (size_t)m * 65536;
            WoT = wtS + (size_t)(4 + m) * 65536;
            WlT = wtS + (size_t)(8 + m) * 65536;
            Wr = (const float*)d_in[13] + (size_t)m * D2 * D2;
            bias  = (const float*)d_in[15] + (size_t)m * D2;
            gamma = (const float*)d_in[16] + (size_t)m * D2;
            beta  = (const float*)d_in[17] + (size_t)m * D2;
        }

        // gathers (both directions) into bf16 agg buffers
        if (K == D1) {
            k_gather<D1><<<NN / 4, 256, 0, stream>>>(xb, rc, csrc_in, cet_in, cnorm_in, off_in, aggI);
            k_gather<D1><<<NN / 4, 256, 0, stream>>>(xb, rc, csrc_out, cet_out, cnorm_out, off_out, aggO);
        } else {
            k_gather<D2><<<NN / 4, 256, 0, stream>>>(xb, rc, csrc_in, cet_in, cnorm_in, off_in, aggI);
            k_gather<D2><<<NN / 4, 256, 0, stream>>>(xb, rc, csrc_out, cet_out, cnorm_out, off_out, aggO);
        }
        // fused 3-segment MFMA GEMM: h = (aggI@Wi + aggO@Wo + x@Wl')/3 + bias
        dim3 ggrid(NN / 128, 2);
        if (K == D1) k_gemm_mfma<D1><<<ggrid, 256, 0, stream>>>(aggI, aggO, xb, WiT, WoT, WlT, bias, h);
        else         k_gemm_mfma<D2><<<ggrid, 256, 0, stream>>>(aggI, aggO, xb, WiT, WoT, WlT, bias, h);
        // batchnorm + relu -> bf16 x (in-place safe: all readers of old x are done)
        hipMemsetAsync(bnsums, 0, 512 * sizeof(float), stream);
        k_bnstats<<<128, 256, 0, stream>>>(h, bnsums);
        k_bnapply<<<(NN * 256) / 256, 256, 0, stream>>>(h, bnsums, gamma, beta, xbfA);
        // relation transform (f32, tiny)
        k_gemm_rel<<<dim3(4, 4), 256, 0, stream>>>(rc, Wr, rn, RR, K);
        const float* nr = rn;
        rn = (l == 0) ? relB : (float*)rc;
        rc = nr;
    }

    k_feats<<<GG, 256, 0, stream>>>(xbfA, rc, rel_labels, feats);
    k_head<<<GG, 256, 0, stream>>>(feats, (const float*)d_in[18],
                                   (const float*)d_in[19], out);
}

// Round 5
// 925.752 us; speedup vs baseline: 10.0597x; 1.1446x over previous
//
#include <hip/hip_runtime.h>

#define NN 32768      // total nodes
#define GG 256        // graphs
#define NPGN 128      // nodes per graph
#define ET 524288     // total directed edges
#define EH 262144     // edges per direction
#define D1 128        // input feature dim
#define D2 256        // hidden dim
#define RR 200        // relations

typedef unsigned short u16;
typedef __attribute__((ext_vector_type(8))) short bf16x8;   // MFMA A/B frag (4 VGPR)
typedef __attribute__((ext_vector_type(4))) float f32x4;    // MFMA C/D frag
typedef __attribute__((ext_vector_type(8))) unsigned short u16x8;
typedef __attribute__((ext_vector_type(4))) unsigned short u16x4;

__device__ __forceinline__ float bf2f(u16 u) {
    union { unsigned int i; float f; } v; v.i = ((unsigned int)u) << 16; return v.f;
}
__device__ __forceinline__ u16 f2bf(float f) {
    union { unsigned int i; float f; } v; v.f = f;
    unsigned int x = v.i;
    return (u16)((x + 0x7fffu + ((x >> 16) & 1u)) >> 16);   // RNE
}

// ---- histograms: by-src (for norm) and by-dst (for CSR) per direction ----
__global__ void k_hist(const int* __restrict__ ei, int* __restrict__ hs_in,
                       int* __restrict__ hs_out, int* __restrict__ hd_in,
                       int* __restrict__ hd_out) {
    int e = blockIdx.x * blockDim.x + threadIdx.x;
    if (e >= ET) return;
    int s = ei[e], d = ei[ET + e];
    if (e < EH) { atomicAdd(&hs_in[s], 1);  atomicAdd(&hd_in[d], 1); }
    else        { atomicAdd(&hs_out[s], 1); atomicAdd(&hd_out[d], 1); }
}

__global__ void k_dinv(const int* __restrict__ hs_in, const int* __restrict__ hs_out,
                       float* __restrict__ dinv_in, float* __restrict__ dinv_out) {
    int n = blockIdx.x * blockDim.x + threadIdx.x;
    if (n >= NN) return;
    int a = hs_in[n], b = hs_out[n];
    dinv_in[n]  = a > 0 ? rsqrtf((float)a) : 0.f;
    dinv_out[n] = b > 0 ? rsqrtf((float)b) : 0.f;
}

// ---- exclusive scan of 32768 ints, single block of 1024 ----
__global__ __launch_bounds__(1024) void k_scan(const int* __restrict__ hist,
                                               int* __restrict__ off) {
    __shared__ int lds[1024];
    int t = threadIdx.x;
    int base = t * 32;
    int loc[32];
    int s = 0;
#pragma unroll
    for (int i = 0; i < 32; ++i) { loc[i] = s; s += hist[base + i]; }
    lds[t] = s;
    int tot = s;
    __syncthreads();
    for (int st = 1; st < 1024; st <<= 1) {
        int v = (t >= st) ? lds[t - st] : 0;
        __syncthreads();
        lds[t] += v;
        __syncthreads();
    }
    int excl = lds[t] - tot;
#pragma unroll
    for (int i = 0; i < 32; ++i) off[base + i] = excl + loc[i];
    if (t == 1023) off[NN] = lds[1023];
}

// ---- fill CSR slots (dst-sorted); norm folded in ----
__global__ void k_fill(const int* __restrict__ ei, const int* __restrict__ et,
                       const float* __restrict__ dinv, const int* __restrict__ off,
                       int* __restrict__ cur, int* __restrict__ c_src,
                       int* __restrict__ c_et, float* __restrict__ c_norm, int eoff) {
    int e = blockIdx.x * blockDim.x + threadIdx.x;
    if (e >= EH) return;
    int s = ei[eoff + e], d = ei[ET + eoff + e], t = et[eoff + e];
    int slot = off[d] + atomicAdd(&cur[d], 1);
    c_src[slot] = s;
    c_et[slot] = t;
    c_norm[slot] = dinv[s] * dinv[d];
}

// ---- f32 -> bf16 ----
__global__ void k_convx(const float* __restrict__ in, u16* __restrict__ out, int n) {
    int i = blockIdx.x * blockDim.x + threadIdx.x;
    if (i < n) out[i] = f2bf(in[i]);
}

// ---- weight prep: Wt[l][n][k] = bf16(W[l][k][n]), lr folded into loop family ----
__global__ void k_prepw(const float* __restrict__ Wi, const float* __restrict__ Wo,
                        const float* __restrict__ Wl, const float* __restrict__ lr,
                        u16* __restrict__ WiT, u16* __restrict__ WoT,
                        u16* __restrict__ WlT, int K, int L) {
    int idx = blockIdx.x * blockDim.x + threadIdx.x;
    int per = L * K * 256;
    if (idx >= 3 * per) return;
    int fam = idx / per, rem = idx % per;
    int l = rem / (K * 256), rr = rem % (K * 256);
    int k = rr / 256, n = rr % 256;
    const float* src = fam == 0 ? Wi : fam == 1 ? Wo : Wl;
    float v = src[((size_t)l * K + k) * 256 + n];
    if (fam == 2) v *= lr[l * K + k];
    u16* dst = fam == 0 ? WiT : fam == 1 ? WoT : WlT;
    dst[((size_t)l * 256 + n) * K + k] = f2bf(v);
}

// ---- gather, both directions: half-wave (32 lanes) per node, 2-edge unroll ----
template <int K>
__global__ __launch_bounds__(256) void k_gather2(
    const u16* __restrict__ x, const u16* __restrict__ relb,
    const int* __restrict__ csI, const int* __restrict__ cetI,
    const float* __restrict__ cnI, const int* __restrict__ offI,
    const int* __restrict__ csO, const int* __restrict__ cetO,
    const float* __restrict__ cnO, const int* __restrict__ offO,
    u16* __restrict__ aggI, u16* __restrict__ aggO) {
    constexpr int VEC = K / 32;
    const int dir = blockIdx.y;
    const int* __restrict__ cs  = dir ? csO : csI;
    const int* __restrict__ cet = dir ? cetO : cetI;
    const float* __restrict__ cn = dir ? cnO : cnI;
    const int* __restrict__ off = dir ? offO : offI;
    u16* __restrict__ agg = dir ? aggO : aggI;

    int node = blockIdx.x * 8 + (threadIdx.x >> 5);
    int l = threadIdx.x & 31;
    int c = l * VEC;
    int e0 = off[node], e1 = off[node + 1];
    float acc[VEC] = {};
    int e = e0;
    for (; e + 2 <= e1; e += 2) {
        int s0 = cs[e],     t0 = cet[e];     float n0 = cn[e];
        int s1 = cs[e + 1], t1 = cet[e + 1]; float n1 = cn[e + 1];
        if constexpr (VEC == 8) {
            u16x8 x0 = *(const u16x8*)(x + (size_t)s0 * K + c);
            u16x8 r0 = *(const u16x8*)(relb + (size_t)t0 * K + c);
            u16x8 x1 = *(const u16x8*)(x + (size_t)s1 * K + c);
            u16x8 r1 = *(const u16x8*)(relb + (size_t)t1 * K + c);
#pragma unroll
            for (int i = 0; i < 8; ++i)
                acc[i] += n0 * bf2f(x0[i]) * bf2f(r0[i]) + n1 * bf2f(x1[i]) * bf2f(r1[i]);
        } else {
            u16x4 x0 = *(const u16x4*)(x + (size_t)s0 * K + c);
            u16x4 r0 = *(const u16x4*)(relb + (size_t)t0 * K + c);
            u16x4 x1 = *(const u16x4*)(x + (size_t)s1 * K + c);
            u16x4 r1 = *(const u16x4*)(relb + (size_t)t1 * K + c);
#pragma unroll
            for (int i = 0; i < 4; ++i)
                acc[i] += n0 * bf2f(x0[i]) * bf2f(r0[i]) + n1 * bf2f(x1[i]) * bf2f(r1[i]);
        }
    }
    if (e < e1) {
        int s0 = cs[e], t0 = cet[e]; float n0 = cn[e];
        if constexpr (VEC == 8) {
            u16x8 x0 = *(const u16x8*)(x + (size_t)s0 * K + c);
            u16x8 r0 = *(const u16x8*)(relb + (size_t)t0 * K + c);
#pragma unroll
            for (int i = 0; i < 8; ++i) acc[i] += n0 * bf2f(x0[i]) * bf2f(r0[i]);
        } else {
            u16x4 x0 = *(const u16x4*)(x + (size_t)s0 * K + c);
            u16x4 r0 = *(const u16x4*)(relb + (size_t)t0 * K + c);
#pragma unroll
            for (int i = 0; i < 4; ++i) acc[i] += n0 * bf2f(x0[i]) * bf2f(r0[i]);
        }
    }
    if constexpr (VEC == 8) {
        u16x8 o;
#pragma unroll
        for (int i = 0; i < 8; ++i) o[i] = f2bf(acc[i]);
        *(u16x8*)(agg + (size_t)node * K + c) = o;
    } else {
        u16x4 o;
#pragma unroll
        for (int i = 0; i < 4; ++i) o[i] = f2bf(acc[i]);
        *(u16x4*)(agg + (size_t)node * K + c) = o;
    }
}

// ---- fused 3-segment MFMA GEMM + BN-stats epilogue ----
// C = (A1@W1t + A2@W2t + A3@W3t)/3 + bias ; bnsums[col] += sum, bnsums[256+col] += sumsq
// Register double-buffered prefetch: step s+1 loads issued before step s MFMAs.
template <int K>
__global__ __launch_bounds__(256) void k_gemm_mfma(
    const u16* __restrict__ A1, const u16* __restrict__ A2, const u16* __restrict__ A3,
    const u16* __restrict__ W1, const u16* __restrict__ W2, const u16* __restrict__ W3,
    const float* __restrict__ bias, float* __restrict__ C, float* __restrict__ bnsums) {
    const int tid = threadIdx.x;
    const int wave = tid >> 6, lane = tid & 63;
    const int q = lane >> 4, r = lane & 15;
    const int rowBase = blockIdx.x * 128 + (wave & 1) * 64;
    const int colBase = blockIdx.y * 128 + (wave >> 1) * 64;
    f32x4 zero = {0.f, 0.f, 0.f, 0.f};
    f32x4 acc[4][4];
#pragma unroll
    for (int i = 0; i < 4; ++i)
#pragma unroll
        for (int j = 0; j < 4; ++j) acc[i][j] = zero;

    const u16* As[3] = {A1, A2, A3};
    const u16* Ws[3] = {W1, W2, W3};
    constexpr int SPS = K / 32;
    constexpr int TOT = 3 * SPS;

    bf16x8 aC[4], bC[4], aN[4], bN[4];
#pragma unroll
    for (int t = 0; t < 4; ++t) {
        aC[t] = *(const bf16x8*)(As[0] + (size_t)(rowBase + t * 16 + r) * K + q * 8);
        bC[t] = *(const bf16x8*)(Ws[0] + (size_t)(colBase + t * 16 + r) * K + q * 8);
    }
#pragma unroll
    for (int s = 0; s < TOT; ++s) {
        if (s + 1 < TOT) {
            const u16* A = As[(s + 1) / SPS];
            const u16* W = Ws[(s + 1) / SPS];
            const int kb = ((s + 1) % SPS) * 32 + q * 8;
#pragma unroll
            for (int t = 0; t < 4; ++t) {
                aN[t] = *(const bf16x8*)(A + (size_t)(rowBase + t * 16 + r) * K + kb);
                bN[t] = *(const bf16x8*)(W + (size_t)(colBase + t * 16 + r) * K + kb);
            }
        }
#pragma unroll
        for (int tm = 0; tm < 4; ++tm)
#pragma unroll
            for (int tn = 0; tn < 4; ++tn)
                acc[tm][tn] = __builtin_amdgcn_mfma_f32_16x16x32_bf16(
                    aC[tm], bC[tn], acc[tm][tn], 0, 0, 0);
#pragma unroll
        for (int t = 0; t < 4; ++t) { aC[t] = aN[t]; bC[t] = bN[t]; }
    }

    // epilogue: store + per-column partial stats
#pragma unroll
    for (int tn = 0; tn < 4; ++tn) {
        int col = colBase + tn * 16 + r;
        float bv = bias[col];
        float sv = 0.f, qv = 0.f;
#pragma unroll
        for (int tm = 0; tm < 4; ++tm) {
#pragma unroll
            for (int reg = 0; reg < 4; ++reg) {
                int row = rowBase + tm * 16 + q * 4 + reg;
                float v = acc[tm][tn][reg] / 3.0f + bv;
                C[(size_t)row * 256 + col] = v;
                sv += v; qv += v * v;
            }
        }
        sv += __shfl_xor(sv, 16); sv += __shfl_xor(sv, 32);
        qv += __shfl_xor(qv, 16); qv += __shfl_xor(qv, 32);
        if (q == 0) {
            atomicAdd(&bnsums[col], sv);
            atomicAdd(&bnsums[256 + col], qv);
        }
    }
}

// ---- small f32 GEMM for relation chain: C = A @ W, plus bf16 copy Cb ----
__global__ __launch_bounds__(256) void k_gemm_rel(
    const float* __restrict__ A, const float* __restrict__ W,
    float* __restrict__ C, u16* __restrict__ Cb, int M, int K) {
    __shared__ float As[16][68];
    __shared__ float Wshm[16][68];
    const int tid = threadIdx.x;
    const int tx = tid & 15, ty = tid >> 4;
    const int arow = tid >> 2;
    const int akc  = (tid & 3) << 2;
    const int wk   = tid >> 4;
    const int wn0  = (tid & 15) << 2;
    const int rowBase = blockIdx.x << 6;
    const int colBase = blockIdx.y << 6;
    float acc[4][4] = {};
    for (int k0 = 0; k0 < K; k0 += 16) {
        float4 av = make_float4(0.f, 0.f, 0.f, 0.f);
        int rr = rowBase + arow;
        if (rr < M) av = *(const float4*)(A + (size_t)rr * K + k0 + akc);
        As[akc + 0][arow] = av.x;
        As[akc + 1][arow] = av.y;
        As[akc + 2][arow] = av.z;
        As[akc + 3][arow] = av.w;
        float4 wv = *(const float4*)(W + (size_t)(k0 + wk) * D2 + colBase + wn0);
        Wshm[wk][wn0 + 0] = wv.x;
        Wshm[wk][wn0 + 1] = wv.y;
        Wshm[wk][wn0 + 2] = wv.z;
        Wshm[wk][wn0 + 3] = wv.w;
        __syncthreads();
#pragma unroll
        for (int kk = 0; kk < 16; ++kk) {
            float a0 = As[kk][(ty << 2) + 0], a1 = As[kk][(ty << 2) + 1];
            float a2 = As[kk][(ty << 2) + 2], a3 = As[kk][(ty << 2) + 3];
            float w0 = Wshm[kk][(tx << 2) + 0], w1 = Wshm[kk][(tx << 2) + 1];
            float w2 = Wshm[kk][(tx << 2) + 2], w3 = Wshm[kk][(tx << 2) + 3];
            acc[0][0] += a0 * w0; acc[0][1] += a0 * w1; acc[0][2] += a0 * w2; acc[0][3] += a0 * w3;
            acc[1][0] += a1 * w0; acc[1][1] += a1 * w1; acc[1][2] += a1 * w2; acc[1][3] += a1 * w3;
            acc[2][0] += a2 * w0; acc[2][1] += a2 * w1; acc[2][2] += a2 * w2; acc[2][3] += a2 * w3;
            acc[3][0] += a3 * w0; acc[3][1] += a3 * w1; acc[3][2] += a3 * w2; acc[3][3] += a3 * w3;
        }
        __syncthreads();
    }
#pragma unroll
    for (int i = 0; i < 4; ++i) {
        int rr = rowBase + (ty << 2) + i;
        if (rr >= M) continue;
        float* cp = C + (size_t)rr * D2 + colBase + (tx << 2);
        u16* cb = Cb + (size_t)rr * D2 + colBase + (tx << 2);
        cp[0] = acc[i][0]; cp[1] = acc[i][1]; cp[2] = acc[i][2]; cp[3] = acc[i][3];
        cb[0] = f2bf(acc[i][0]); cb[1] = f2bf(acc[i][1]);
        cb[2] = f2bf(acc[i][2]); cb[3] = f2bf(acc[i][3]);
    }
}

// ---- BN apply + ReLU, 4 elems/thread, emit bf16 x ----
__global__ void k_bnapply(const float4* __restrict__ h4, const float* __restrict__ sums,
                          const float* __restrict__ gamma, const float* __restrict__ beta,
                          u16x4* __restrict__ xb4) {
    int idx = blockIdx.x * blockDim.x + threadIdx.x;
    int f0 = (idx & 63) << 2;
    float4 v = h4[idx];
    u16x4 o;
    float vv[4] = {v.x, v.y, v.z, v.w};
#pragma unroll
    for (int i = 0; i < 4; ++i) {
        int f = f0 + i;
        float mean = sums[f] * (1.0f / NN);
        float var  = sums[256 + f] * (1.0f / NN) - mean * mean;
        float inv  = 1.0f / sqrtf(var + 1e-5f);
        float t = (vv[i] - mean) * inv * gamma[f] + beta[f];
        o[i] = f2bf(t > 0.f ? t : 0.f);
    }
    xb4[idx] = o;
}

// ---- head features ----
__global__ void k_feats(const u16* __restrict__ x, const float* __restrict__ rel,
                        const int* __restrict__ rel_labels, float* __restrict__ feats) {
    int g = blockIdx.x, f = threadIdx.x;
    const u16* xg = x + (size_t)g * NPGN * D2;
    float s = 0.f;
#pragma unroll 8
    for (int n = 0; n < NPGN; ++n) s += bf2f(xg[(size_t)n * D2 + f]);
    float* fg = feats + (size_t)g * 1024;
    fg[f]       = s * (1.0f / NPGN);
    fg[256 + f] = rel[(size_t)rel_labels[g] * D2 + f];
    fg[512 + f] = bf2f(xg[f]);
    fg[768 + f] = bf2f(xg[D2 + f]);
}

// ---- final linear ----
__global__ void k_head(const float* __restrict__ feats, const float* __restrict__ lw,
                       const float* __restrict__ lb, float* __restrict__ out) {
    int g = blockIdx.x, t = threadIdx.x;
    __shared__ float s0[256], s1[256];
    float a0 = 0.f, a1 = 0.f;
#pragma unroll
    for (int j = 0; j < 4; ++j) {
        int k = t * 4 + j;
        float fv = feats[(size_t)g * 1024 + k];
        a0 += fv * lw[k * 2 + 0];
        a1 += fv * lw[k * 2 + 1];
    }
    s0[t] = a0; s1[t] = a1;
    __syncthreads();
    for (int s = 128; s > 0; s >>= 1) {
        if (t < s) { s0[t] += s0[t + s]; s1[t] += s1[t + s]; }
        __syncthreads();
    }
    if (t == 0) {
        out[g * 2 + 0] = s0[0] + lb[0];
        out[g * 2 + 1] = s1[0] + lb[1];
    }
}

extern "C" void kernel_launch(void* const* d_in, const int* in_sizes, int n_in,
                              void* d_out, int out_size, void* d_ws, size_t ws_size,
                              hipStream_t stream) {
    const float* x0   = (const float*)d_in[0];
    const float* rel0 = (const float*)d_in[1];
    const int* edge_index = (const int*)d_in[20];
    const int* edge_type  = (const int*)d_in[21];
    const int* rel_labels = (const int*)d_in[23];
    float* out = (float*)d_out;

    // ---- workspace carve ----
    float* ws = (float*)d_ws;
    float* h     = ws;                              // NN*256 f32
    float* relA  = h + (size_t)NN * 256;            // RR*256
    float* relB  = relA + (size_t)RR * 256;         // RR*256
    float* dinv_in  = relB + (size_t)RR * 256;      // NN
    float* dinv_out = dinv_in + NN;                 // NN
    float* cnorm_in  = dinv_out + NN;               // EH
    float* cnorm_out = cnorm_in + EH;               // EH
    float* bnsums    = cnorm_out + EH;              // 512
    float* feats     = bnsums + 512;                // GG*1024
    int* csrc_in  = (int*)(feats + GG * 1024);      // EH
    int* cet_in   = csrc_in + EH;                   // EH
    int* csrc_out = cet_in + EH;                    // EH
    int* cet_out  = csrc_out + EH;                  // EH
    int* off_in   = cet_out + EH;                   // NN+8
    int* off_out  = off_in + NN + 8;                // NN+8
    int* hs_in    = off_out + NN + 8;               // NN  -- zeroed region start
    int* hs_out   = hs_in + NN;                     // NN
    int* hd_in    = hs_out + NN;                    // NN
    int* hd_out   = hd_in + NN;                     // NN
    int* cur_in   = hd_out + NN;                    // NN
    int* cur_out  = cur_in + NN;                    // NN
    u16* xbf0 = (u16*)(cur_out + NN);               // NN*128 bf16
    u16* xbfA = xbf0 + (size_t)NN * 128;            // NN*256 bf16
    u16* aggI = xbfA + (size_t)NN * 256;            // NN*256 bf16
    u16* aggO = aggI + (size_t)NN * 256;            // NN*256 bf16
    u16* wt0  = aggO + (size_t)NN * 256;            // 3*256*128
    u16* wtS  = wt0 + 3 * 256 * 128;                // 12*256*256
    u16* relbf = wtS + 12 * 65536;                  // RR*256 bf16

    // ---- CSR build + conversions + weight prep (once per launch) ----
    hipMemsetAsync(hs_in, 0, 6 * NN * sizeof(int), stream);
    k_hist<<<ET / 256, 256, 0, stream>>>(edge_index, hs_in, hs_out, hd_in, hd_out);
    k_dinv<<<NN / 256, 256, 0, stream>>>(hs_in, hs_out, dinv_in, dinv_out);
    k_scan<<<1, 1024, 0, stream>>>(hd_in, off_in);
    k_scan<<<1, 1024, 0, stream>>>(hd_out, off_out);
    k_fill<<<EH / 256, 256, 0, stream>>>(edge_index, edge_type, dinv_in, off_in,
                                         cur_in, csrc_in, cet_in, cnorm_in, 0);
    k_fill<<<EH / 256, 256, 0, stream>>>(edge_index, edge_type, dinv_out, off_out,
                                         cur_out, csrc_out, cet_out, cnorm_out, EH);
    k_convx<<<(NN * D1) / 256, 256, 0, stream>>>(x0, xbf0, NN * D1);
    k_convx<<<(RR * D1 + 255) / 256, 256, 0, stream>>>(rel0, relbf, RR * D1);
    k_prepw<<<(3 * D1 * 256) / 256, 256, 0, stream>>>(
        (const float*)d_in[2], (const float*)d_in[3], (const float*)d_in[4],
        (const float*)d_in[6], wt0, wt0 + 256 * D1, wt0 + 2 * 256 * D1, D1, 1);
    k_prepw<<<(3 * 4 * D2 * 256) / 256, 256, 0, stream>>>(
        (const float*)d_in[10], (const float*)d_in[11], (const float*)d_in[12],
        (const float*)d_in[14], wtS, wtS + 4 * 65536, wtS + 8 * 65536, D2, 4);

    const float* rc = rel0; float* rn = relA;

    for (int l = 0; l < 5; ++l) {
        const int K = (l == 0) ? D1 : D2;
        const u16* xb = (l == 0) ? xbf0 : xbfA;
        const u16 *WiT, *WoT, *WlT;
        const float *Wr, *bias, *gamma, *beta;
        if (l == 0) {
            WiT = wt0; WoT = wt0 + 256 * D1; WlT = wt0 + 2 * 256 * D1;
            Wr = (const float*)d_in[5];
            bias  = (const float*)d_in[7];
            gamma = (const float*)d_in[8];
            beta  = (const float*)d_in[9];
        } else {
            int m = l - 1;
            WiT = wtS + (size_t)m * 65536;
            WoT = wtS + (size_t)(4 + m) * 65536;
            WlT = wtS + (size_t)(8 + m) * 65536;
            Wr = (const float*)d_in[13] + (size_t)m * D2 * D2;
            bias  = (const float*)d_in[15] + (size_t)m * D2;
            gamma = (const float*)d_in[16] + (size_t)m * D2;
            beta  = (const float*)d_in[17] + (size_t)m * D2;
        }

        // both-direction gather into bf16 agg buffers
        dim3 ggr(NN / 8, 2);
        if (K == D1) k_gather2<D1><<<ggr, 256, 0, stream>>>(xb, relbf, csrc_in, cet_in,
            cnorm_in, off_in, csrc_out, cet_out, cnorm_out, off_out, aggI, aggO);
        else         k_gather2<D2><<<ggr, 256, 0, stream>>>(xb, relbf, csrc_in, cet_in,
            cnorm_in, off_in, csrc_out, cet_out, cnorm_out, off_out, aggI, aggO);
        // fused 3-segment MFMA GEMM + BN stats
        hipMemsetAsync(bnsums, 0, 512 * sizeof(float), stream);
        dim3 ggrid(NN / 128, 2);
        if (K == D1) k_gemm_mfma<D1><<<ggrid, 256, 0, stream>>>(aggI, aggO, xb, WiT, WoT, WlT, bias, h, bnsums);
        else         k_gemm_mfma<D2><<<ggrid, 256, 0, stream>>>(aggI, aggO, xb, WiT, WoT, WlT, bias, h, bnsums);
        // BN apply + relu -> bf16 x
        k_bnapply<<<(NN * 256 / 4) / 256, 256, 0, stream>>>((const float4*)h, bnsums,
                                                            gamma, beta, (u16x4*)xbfA);
        // relation transform (f32 chain + bf16 copy for gathers)
        k_gemm_rel<<<dim3(4, 4), 256, 0, stream>>>(rc, Wr, rn, relbf, RR, K);
        const float* nr = rn;
        rn = (l == 0) ? relB : (float*)rc;
        rc = nr;
    }

    k_feats<<<GG, 256, 0, stream>>>(xbfA, rc, rel_labels, feats);
    k_head<<<GG, 256, 0, stream>>>(feats, (const float*)d_in[18],
                                   (const float*)d_in[19], out);
}

// Round 6
// 829.458 us; speedup vs baseline: 11.2276x; 1.1161x over previous
//
#include <hip/hip_runtime.h>

#define NN 32768      // total nodes
#define GG 256        // graphs
#define NPGN 128      // nodes per graph
#define ET 524288     // total directed edges
#define EH 262144     // edges per direction
#define D1 128        // input feature dim
#define D2 256        // hidden dim
#define RR 200        // relations

typedef unsigned short u16;
typedef __attribute__((ext_vector_type(8))) short bf16x8;   // MFMA A/B frag (4 VGPR)
typedef __attribute__((ext_vector_type(4))) float f32x4;    // MFMA C/D frag
typedef __attribute__((ext_vector_type(8))) unsigned short u16x8;
typedef __attribute__((ext_vector_type(4))) unsigned short u16x4;

__device__ __forceinline__ float bf2f(u16 u) {
    union { unsigned int i; float f; } v; v.i = ((unsigned int)u) << 16; return v.f;
}
__device__ __forceinline__ u16 f2bf(float f) {
    union { unsigned int i; float f; } v; v.f = f;
    unsigned int x = v.i;
    return (u16)((x + 0x7fffu + ((x >> 16) & 1u)) >> 16);   // RNE
}

// ---- histograms: by-src (for norm) and by-dst (for CSR) per direction ----
__global__ void k_hist(const int* __restrict__ ei, int* __restrict__ hs_in,
                       int* __restrict__ hs_out, int* __restrict__ hd_in,
                       int* __restrict__ hd_out) {
    int e = blockIdx.x * blockDim.x + threadIdx.x;
    if (e >= ET) return;
    int s = ei[e], d = ei[ET + e];
    if (e < EH) { atomicAdd(&hs_in[s], 1);  atomicAdd(&hd_in[d], 1); }
    else        { atomicAdd(&hs_out[s], 1); atomicAdd(&hd_out[d], 1); }
}

__global__ void k_dinv(const int* __restrict__ hs_in, const int* __restrict__ hs_out,
                       float* __restrict__ dinv_in, float* __restrict__ dinv_out) {
    int n = blockIdx.x * blockDim.x + threadIdx.x;
    if (n >= NN) return;
    int a = hs_in[n], b = hs_out[n];
    dinv_in[n]  = a > 0 ? rsqrtf((float)a) : 0.f;
    dinv_out[n] = b > 0 ? rsqrtf((float)b) : 0.f;
}

// ---- exclusive scan of 32768 ints, single block of 1024 ----
__global__ __launch_bounds__(1024) void k_scan(const int* __restrict__ hist,
                                               int* __restrict__ off) {
    __shared__ int lds[1024];
    int t = threadIdx.x;
    int base = t * 32;
    int loc[32];
    int s = 0;
#pragma unroll
    for (int i = 0; i < 32; ++i) { loc[i] = s; s += hist[base + i]; }
    lds[t] = s;
    int tot = s;
    __syncthreads();
    for (int st = 1; st < 1024; st <<= 1) {
        int v = (t >= st) ? lds[t - st] : 0;
        __syncthreads();
        lds[t] += v;
        __syncthreads();
    }
    int excl = lds[t] - tot;
#pragma unroll
    for (int i = 0; i < 32; ++i) off[base + i] = excl + loc[i];
    if (t == 1023) off[NN] = lds[1023];
}

// ---- fill CSR slots (dst-sorted); norm folded in ----
__global__ void k_fill(const int* __restrict__ ei, const int* __restrict__ et,
                       const float* __restrict__ dinv, const int* __restrict__ off,
                       int* __restrict__ cur, int* __restrict__ c_src,
                       int* __restrict__ c_et, float* __restrict__ c_norm, int eoff) {
    int e = blockIdx.x * blockDim.x + threadIdx.x;
    if (e >= EH) return;
    int s = ei[eoff + e], d = ei[ET + eoff + e], t = et[eoff + e];
    int slot = off[d] + atomicAdd(&cur[d], 1);
    c_src[slot] = s;
    c_et[slot] = t;
    c_norm[slot] = dinv[s] * dinv[d];
}

// ---- f32 -> bf16 ----
__global__ void k_convx(const float* __restrict__ in, u16* __restrict__ out, int n) {
    int i = blockIdx.x * blockDim.x + threadIdx.x;
    if (i < n) out[i] = f2bf(in[i]);
}

// ---- weight prep: Wt[l][n][k] = bf16(W[l][k][n]), lr folded into loop family ----
__global__ void k_prepw(const float* __restrict__ Wi, const float* __restrict__ Wo,
                        const float* __restrict__ Wl, const float* __restrict__ lr,
                        u16* __restrict__ WiT, u16* __restrict__ WoT,
                        u16* __restrict__ WlT, int K, int L) {
    int idx = blockIdx.x * blockDim.x + threadIdx.x;
    int per = L * K * 256;
    if (idx >= 3 * per) return;
    int fam = idx / per, rem = idx % per;
    int l = rem / (K * 256), rr = rem % (K * 256);
    int k = rr / 256, n = rr % 256;
    const float* src = fam == 0 ? Wi : fam == 1 ? Wo : Wl;
    float v = src[((size_t)l * K + k) * 256 + n];
    if (fam == 2) v *= lr[l * K + k];
    u16* dst = fam == 0 ? WiT : fam == 1 ? WoT : WlT;
    dst[((size_t)l * 256 + n) * K + k] = f2bf(v);
}

// ---- gather, both directions: K/8 lanes per node (16B frags), 4-edge unroll ----
template <int K>
__global__ __launch_bounds__(256) void k_gather2(
    const u16* __restrict__ x, const u16* __restrict__ relb,
    const int* __restrict__ csI, const int* __restrict__ cetI,
    const float* __restrict__ cnI, const int* __restrict__ offI,
    const int* __restrict__ csO, const int* __restrict__ cetO,
    const float* __restrict__ cnO, const int* __restrict__ offO,
    u16* __restrict__ aggI, u16* __restrict__ aggO) {
    constexpr int LPN = K / 8;            // lanes per node
    constexpr int NPB = 256 / LPN;        // nodes per block
    const int dir = blockIdx.y;
    const int* __restrict__ cs  = dir ? csO : csI;
    const int* __restrict__ cet = dir ? cetO : cetI;
    const float* __restrict__ cn = dir ? cnO : cnI;
    const int* __restrict__ off = dir ? offO : offI;
    u16* __restrict__ agg = dir ? aggO : aggI;

    int node = blockIdx.x * NPB + (threadIdx.x / LPN);
    int lane = threadIdx.x % LPN;
    int c = lane * 8;
    int e0 = off[node], e1 = off[node + 1];
    float acc[8] = {};
    int e = e0;
    for (; e + 4 <= e1; e += 4) {
        int s0 = cs[e],     s1 = cs[e + 1], s2 = cs[e + 2], s3 = cs[e + 3];
        int t0 = cet[e],    t1 = cet[e + 1], t2 = cet[e + 2], t3 = cet[e + 3];
        float n0 = cn[e], n1 = cn[e + 1], n2 = cn[e + 2], n3 = cn[e + 3];
        u16x8 xa = *(const u16x8*)(x + (size_t)s0 * K + c);
        u16x8 xb = *(const u16x8*)(x + (size_t)s1 * K + c);
        u16x8 xc = *(const u16x8*)(x + (size_t)s2 * K + c);
        u16x8 xd = *(const u16x8*)(x + (size_t)s3 * K + c);
        u16x8 ra = *(const u16x8*)(relb + (size_t)t0 * K + c);
        u16x8 rb = *(const u16x8*)(relb + (size_t)t1 * K + c);
        u16x8 rc = *(const u16x8*)(relb + (size_t)t2 * K + c);
        u16x8 rd = *(const u16x8*)(relb + (size_t)t3 * K + c);
#pragma unroll
        for (int i = 0; i < 8; ++i)
            acc[i] += n0 * bf2f(xa[i]) * bf2f(ra[i]) + n1 * bf2f(xb[i]) * bf2f(rb[i])
                    + n2 * bf2f(xc[i]) * bf2f(rc[i]) + n3 * bf2f(xd[i]) * bf2f(rd[i]);
    }
    for (; e < e1; ++e) {
        int s0 = cs[e], t0 = cet[e]; float n0 = cn[e];
        u16x8 xa = *(const u16x8*)(x + (size_t)s0 * K + c);
        u16x8 ra = *(const u16x8*)(relb + (size_t)t0 * K + c);
#pragma unroll
        for (int i = 0; i < 8; ++i) acc[i] += n0 * bf2f(xa[i]) * bf2f(ra[i]);
    }
    u16x8 o;
#pragma unroll
    for (int i = 0; i < 8; ++i) o[i] = f2bf(acc[i]);
    *(u16x8*)(agg + (size_t)node * K + c) = o;
}

// ---- async stage of one [128][32] bf16 tile into LDS via global_load_lds x16 ----
// LDS layout: [row][k] contiguous (8 KB). Wave w covers chunks {2w, 2w+1},
// chunk = 16 rows = 64 lanes x 16 B; HW scatters lane i to base + i*16.
__device__ __forceinline__ void stage_tile(const u16* __restrict__ src, int baseRow,
                                           int K, int kk, u16* lds, int wave, int lane) {
#pragma unroll
    for (int i = 0; i < 2; ++i) {
        int chunk = wave * 2 + i;
        int row = chunk * 16 + (lane >> 2);
        const u16* g = src + (size_t)(baseRow + row) * K + kk + (lane & 3) * 8;
        u16* l = lds + chunk * 512;   // wave-uniform base
        __builtin_amdgcn_global_load_lds((const __attribute__((address_space(1))) void*)g,
                                         (__attribute__((address_space(3))) void*)l,
                                         16, 0, 0);
    }
}

// ---- fused 3-segment MFMA GEMM (m97-style LDS pipeline) + BN-stats epilogue ----
// C = (A1@W1t + A2@W2t + A3@W3t)/3 + bias ; bnsums[col]+=sum, bnsums[256+col]+=sumsq
template <int K>
__global__ __launch_bounds__(256) void k_gemm_mfma(
    const u16* __restrict__ A1, const u16* __restrict__ A2, const u16* __restrict__ A3,
    const u16* __restrict__ W1, const u16* __restrict__ W2, const u16* __restrict__ W3,
    const float* __restrict__ bias, float* __restrict__ C, float* __restrict__ bnsums) {
    __shared__ u16 As_s[2][128 * 32];
    __shared__ u16 Ws_s[2][128 * 32];
    const int tid = threadIdx.x;
    const int wave = tid >> 6, lane = tid & 63;
    const int q = lane >> 4, r = lane & 15;
    const int rowBlk = blockIdx.x * 128;
    const int colBlk = blockIdx.y * 128;
    const int rowBase = rowBlk + (wave & 1) * 64;
    const int colBase = colBlk + (wave >> 1) * 64;

    f32x4 zero = {0.f, 0.f, 0.f, 0.f};
    f32x4 acc[4][4];
#pragma unroll
    for (int i = 0; i < 4; ++i)
#pragma unroll
        for (int j = 0; j < 4; ++j) acc[i][j] = zero;

    const u16* As[3] = {A1, A2, A3};
    const u16* Ws[3] = {W1, W2, W3};
    constexpr int SPS = K / 32;
    constexpr int TOT = 3 * SPS;

    // prologue: stage step 0 into buffer 0
    stage_tile(As[0], rowBlk, K, 0, As_s[0], wave, lane);
    stage_tile(Ws[0], colBlk, K, 0, Ws_s[0], wave, lane);

    for (int s = 0; s < TOT; ++s) {
        __syncthreads();   // drains vmcnt: staging of buf[s&1] complete for all waves
        if (s + 1 < TOT) {
            int seg = (s + 1) / SPS;
            int kk  = ((s + 1) % SPS) * 32;
            stage_tile(As[seg], rowBlk, K, kk, As_s[(s + 1) & 1], wave, lane);
            stage_tile(Ws[seg], colBlk, K, kk, Ws_s[(s + 1) & 1], wave, lane);
        }
        const u16* al = As_s[s & 1] + (wave & 1) * 64 * 32;
        const u16* wl = Ws_s[s & 1] + (wave >> 1) * 64 * 32;
        bf16x8 a[4], b[4];
#pragma unroll
        for (int t = 0; t < 4; ++t) {
            a[t] = *(const bf16x8*)(al + (t * 16 + r) * 32 + q * 8);
            b[t] = *(const bf16x8*)(wl + (t * 16 + r) * 32 + q * 8);
        }
#pragma unroll
        for (int tm = 0; tm < 4; ++tm)
#pragma unroll
            for (int tn = 0; tn < 4; ++tn)
                acc[tm][tn] = __builtin_amdgcn_mfma_f32_16x16x32_bf16(
                    a[tm], b[tn], acc[tm][tn], 0, 0, 0);
    }

    // epilogue: store + per-column partial stats
#pragma unroll
    for (int tn = 0; tn < 4; ++tn) {
        int col = colBase + tn * 16 + r;
        float bv = bias[col];
        float sv = 0.f, qv = 0.f;
#pragma unroll
        for (int tm = 0; tm < 4; ++tm) {
#pragma unroll
            for (int reg = 0; reg < 4; ++reg) {
                int row = rowBase + tm * 16 + q * 4 + reg;
                float v = acc[tm][tn][reg] / 3.0f + bv;
                C[(size_t)row * 256 + col] = v;
                sv += v; qv += v * v;
            }
        }
        sv += __shfl_xor(sv, 16); sv += __shfl_xor(sv, 32);
        qv += __shfl_xor(qv, 16); qv += __shfl_xor(qv, 32);
        if (q == 0) {
            atomicAdd(&bnsums[col], sv);
            atomicAdd(&bnsums[256 + col], qv);
        }
    }
}

// ---- small f32 GEMM for relation chain: C = A @ W, plus bf16 copy Cb ----
__global__ __launch_bounds__(256) void k_gemm_rel(
    const float* __restrict__ A, const float* __restrict__ W,
    float* __restrict__ C, u16* __restrict__ Cb, int M, int K) {
    __shared__ float As[16][68];
    __shared__ float Wshm[16][68];
    const int tid = threadIdx.x;
    const int tx = tid & 15, ty = tid >> 4;
    const int arow = tid >> 2;
    const int akc  = (tid & 3) << 2;
    const int wk   = tid >> 4;
    const int wn0  = (tid & 15) << 2;
    const int rowBase = blockIdx.x << 6;
    const int colBase = blockIdx.y << 6;
    float acc[4][4] = {};
    for (int k0 = 0; k0 < K; k0 += 16) {
        float4 av = make_float4(0.f, 0.f, 0.f, 0.f);
        int rr = rowBase + arow;
        if (rr < M) av = *(const float4*)(A + (size_t)rr * K + k0 + akc);
        As[akc + 0][arow] = av.x;
        As[akc + 1][arow] = av.y;
        As[akc + 2][arow] = av.z;
        As[akc + 3][arow] = av.w;
        float4 wv = *(const float4*)(W + (size_t)(k0 + wk) * D2 + colBase + wn0);
        Wshm[wk][wn0 + 0] = wv.x;
        Wshm[wk][wn0 + 1] = wv.y;
        Wshm[wk][wn0 + 2] = wv.z;
        Wshm[wk][wn0 + 3] = wv.w;
        __syncthreads();
#pragma unroll
        for (int kk = 0; kk < 16; ++kk) {
            float a0 = As[kk][(ty << 2) + 0], a1 = As[kk][(ty << 2) + 1];
            float a2 = As[kk][(ty << 2) + 2], a3 = As[kk][(ty << 2) + 3];
            float w0 = Wshm[kk][(tx << 2) + 0], w1 = Wshm[kk][(tx << 2) + 1];
            float w2 = Wshm[kk][(tx << 2) + 2], w3 = Wshm[kk][(tx << 2) + 3];
            acc[0][0] += a0 * w0; acc[0][1] += a0 * w1; acc[0][2] += a0 * w2; acc[0][3] += a0 * w3;
            acc[1][0] += a1 * w0; acc[1][1] += a1 * w1; acc[1][2] += a1 * w2; acc[1][3] += a1 * w3;
            acc[2][0] += a2 * w0; acc[2][1] += a2 * w1; acc[2][2] += a2 * w2; acc[2][3] += a2 * w3;
            acc[3][0] += a3 * w0; acc[3][1] += a3 * w1; acc[3][2] += a3 * w2; acc[3][3] += a3 * w3;
        }
        __syncthreads();
    }
#pragma unroll
    for (int i = 0; i < 4; ++i) {
        int rr = rowBase + (ty << 2) + i;
        if (rr >= M) continue;
        float* cp = C + (size_t)rr * D2 + colBase + (tx << 2);
        u16* cb = Cb + (size_t)rr * D2 + colBase + (tx << 2);
        cp[0] = acc[i][0]; cp[1] = acc[i][1]; cp[2] = acc[i][2]; cp[3] = acc[i][3];
        cb[0] = f2bf(acc[i][0]); cb[1] = f2bf(acc[i][1]);
        cb[2] = f2bf(acc[i][2]); cb[3] = f2bf(acc[i][3]);
    }
}

// ---- BN apply + ReLU, 4 elems/thread, emit bf16 x ----
__global__ void k_bnapply(const float4* __restrict__ h4, const float* __restrict__ sums,
                          const float* __restrict__ gamma, const float* __restrict__ beta,
                          u16x4* __restrict__ xb4) {
    int idx = blockIdx.x * blockDim.x + threadIdx.x;
    int f0 = (idx & 63) << 2;
    float4 v = h4[idx];
    u16x4 o;
    float vv[4] = {v.x, v.y, v.z, v.w};
#pragma unroll
    for (int i = 0; i < 4; ++i) {
        int f = f0 + i;
        float mean = sums[f] * (1.0f / NN);
        float var  = sums[256 + f] * (1.0f / NN) - mean * mean;
        float inv  = 1.0f / sqrtf(var + 1e-5f);
        float t = (vv[i] - mean) * inv * gamma[f] + beta[f];
        o[i] = f2bf(t > 0.f ? t : 0.f);
    }
    xb4[idx] = o;
}

// ---- head features ----
__global__ void k_feats(const u16* __restrict__ x, const float* __restrict__ rel,
                        const int* __restrict__ rel_labels, float* __restrict__ feats) {
    int g = blockIdx.x, f = threadIdx.x;
    const u16* xg = x + (size_t)g * NPGN * D2;
    float s = 0.f;
#pragma unroll 8
    for (int n = 0; n < NPGN; ++n) s += bf2f(xg[(size_t)n * D2 + f]);
    float* fg = feats + (size_t)g * 1024;
    fg[f]       = s * (1.0f / NPGN);
    fg[256 + f] = rel[(size_t)rel_labels[g] * D2 + f];
    fg[512 + f] = bf2f(xg[f]);
    fg[768 + f] = bf2f(xg[D2 + f]);
}

// ---- final linear ----
__global__ void k_head(const float* __restrict__ feats, const float* __restrict__ lw,
                       const float* __restrict__ lb, float* __restrict__ out) {
    int g = blockIdx.x, t = threadIdx.x;
    __shared__ float s0[256], s1[256];
    float a0 = 0.f, a1 = 0.f;
#pragma unroll
    for (int j = 0; j < 4; ++j) {
        int k = t * 4 + j;
        float fv = feats[(size_t)g * 1024 + k];
        a0 += fv * lw[k * 2 + 0];
        a1 += fv * lw[k * 2 + 1];
    }
    s0[t] = a0; s1[t] = a1;
    __syncthreads();
    for (int s = 128; s > 0; s >>= 1) {
        if (t < s) { s0[t] += s0[t + s]; s1[t] += s1[t + s]; }
        __syncthreads();
    }
    if (t == 0) {
        out[g * 2 + 0] = s0[0] + lb[0];
        out[g * 2 + 1] = s1[0] + lb[1];
    }
}

extern "C" void kernel_launch(void* const* d_in, const int* in_sizes, int n_in,
                              void* d_out, int out_size, void* d_ws, size_t ws_size,
                              hipStream_t stream) {
    const float* x0   = (const float*)d_in[0];
    const float* rel0 = (const float*)d_in[1];
    const int* edge_index = (const int*)d_in[20];
    const int* edge_type  = (const int*)d_in[21];
    const int* rel_labels = (const int*)d_in[23];
    float* out = (float*)d_out;

    // ---- workspace carve ----
    float* ws = (float*)d_ws;
    float* h     = ws;                              // NN*256 f32
    float* relA  = h + (size_t)NN * 256;            // RR*256
    float* relB  = relA + (size_t)RR * 256;         // RR*256
    float* dinv_in  = relB + (size_t)RR * 256;      // NN
    float* dinv_out = dinv_in + NN;                 // NN
    float* cnorm_in  = dinv_out + NN;               // EH
    float* cnorm_out = cnorm_in + EH;               // EH
    float* bnsums    = cnorm_out + EH;              // 512
    float* feats     = bnsums + 512;                // GG*1024
    int* csrc_in  = (int*)(feats + GG * 1024);      // EH
    int* cet_in   = csrc_in + EH;                   // EH
    int* csrc_out = cet_in + EH;                    // EH
    int* cet_out  = csrc_out + EH;                  // EH
    int* off_in   = cet_out + EH;                   // NN+8
    int* off_out  = off_in + NN + 8;                // NN+8
    int* hs_in    = off_out + NN + 8;               // NN  -- zeroed region start
    int* hs_out   = hs_in + NN;                     // NN
    int* hd_in    = hs_out + NN;                    // NN
    int* hd_out   = hd_in + NN;                     // NN
    int* cur_in   = hd_out + NN;                    // NN
    int* cur_out  = cur_in + NN;                    // NN
    u16* xbf0 = (u16*)(cur_out + NN);               // NN*128 bf16
    u16* xbfA = xbf0 + (size_t)NN * 128;            // NN*256 bf16
    u16* aggI = xbfA + (size_t)NN * 256;            // NN*256 bf16
    u16* aggO = aggI + (size_t)NN * 256;            // NN*256 bf16
    u16* wt0  = aggO + (size_t)NN * 256;            // 3*256*128
    u16* wtS  = wt0 + 3 * 256 * 128;                // 12*256*256
    u16* relbf = wtS + 12 * 65536;                  // RR*256 bf16

    // ---- CSR build + conversions + weight prep (once per launch) ----
    hipMemsetAsync(hs_in, 0, 6 * NN * sizeof(int), stream);
    k_hist<<<ET / 256, 256, 0, stream>>>(edge_index, hs_in, hs_out, hd_in, hd_out);
    k_dinv<<<NN / 256, 256, 0, stream>>>(hs_in, hs_out, dinv_in, dinv_out);
    k_scan<<<1, 1024, 0, stream>>>(hd_in, off_in);
    k_scan<<<1, 1024, 0, stream>>>(hd_out, off_out);
    k_fill<<<EH / 256, 256, 0, stream>>>(edge_index, edge_type, dinv_in, off_in,
                                         cur_in, csrc_in, cet_in, cnorm_in, 0);
    k_fill<<<EH / 256, 256, 0, stream>>>(edge_index, edge_type, dinv_out, off_out,
                                         cur_out, csrc_out, cet_out, cnorm_out, EH);
    k_convx<<<(NN * D1) / 256, 256, 0, stream>>>(x0, xbf0, NN * D1);
    k_convx<<<(RR * D1 + 255) / 256, 256, 0, stream>>>(rel0, relbf, RR * D1);
    k_prepw<<<(3 * D1 * 256) / 256, 256, 0, stream>>>(
        (const float*)d_in[2], (const float*)d_in[3], (const float*)d_in[4],
        (const float*)d_in[6], wt0, wt0 + 256 * D1, wt0 + 2 * 256 * D1, D1, 1);
    k_prepw<<<(3 * 4 * D2 * 256) / 256, 256, 0, stream>>>(
        (const float*)d_in[10], (const float*)d_in[11], (const float*)d_in[12],
        (const float*)d_in[14], wtS, wtS + 4 * 65536, wtS + 8 * 65536, D2, 4);

    const float* rc = rel0; float* rn = relA;

    for (int l = 0; l < 5; ++l) {
        const int K = (l == 0) ? D1 : D2;
        const u16* xb = (l == 0) ? xbf0 : xbfA;
        const u16 *WiT, *WoT, *WlT;
        const float *Wr, *bias, *gamma, *beta;
        if (l == 0) {
            WiT = wt0; WoT = wt0 + 256 * D1; WlT = wt0 + 2 * 256 * D1;
            Wr = (const float*)d_in[5];
            bias  = (const float*)d_in[7];
            gamma = (const float*)d_in[8];
            beta  = (const float*)d_in[9];
        } else {
            int m = l - 1;
            WiT = wtS + (size_t)m * 65536;
            WoT = wtS + (size_t)(4 + m) * 65536;
            WlT = wtS + (size_t)(8 + m) * 65536;
            Wr = (const float*)d_in[13] + (size_t)m * D2 * D2;
            bias  = (const float*)d_in[15] + (size_t)m * D2;
            gamma = (const float*)d_in[16] + (size_t)m * D2;
            beta  = (const float*)d_in[17] + (size_t)m * D2;
        }

        // both-direction gather into bf16 agg buffers
        if (K == D1) {
            dim3 ggr(NN / 16, 2);
            k_gather2<D1><<<ggr, 256, 0, stream>>>(xb, relbf, csrc_in, cet_in,
                cnorm_in, off_in, csrc_out, cet_out, cnorm_out, off_out, aggI, aggO);
        } else {
            dim3 ggr(NN / 8, 2);
            k_gather2<D2><<<ggr, 256, 0, stream>>>(xb, relbf, csrc_in, cet_in,
                cnorm_in, off_in, csrc_out, cet_out, cnorm_out, off_out, aggI, aggO);
        }
        // fused 3-segment MFMA GEMM (LDS pipeline) + BN stats
        hipMemsetAsync(bnsums, 0, 512 * sizeof(float), stream);
        dim3 ggrid(NN / 128, 2);
        if (K == D1) k_gemm_mfma<D1><<<ggrid, 256, 0, stream>>>(aggI, aggO, xb, WiT, WoT, WlT, bias, h, bnsums);
        else         k_gemm_mfma<D2><<<ggrid, 256, 0, stream>>>(aggI, aggO, xb, WiT, WoT, WlT, bias, h, bnsums);
        // BN apply + relu -> bf16 x
        k_bnapply<<<(NN * 256 / 4) / 256, 256, 0, stream>>>((const float4*)h, bnsums,
                                                            gamma, beta, (u16x4*)xbfA);
        // relation transform (f32 chain + bf16 copy for gathers)
        k_gemm_rel<<<dim3(4, 4), 256, 0, stream>>>(rc, Wr, rn, relbf, RR, K);
        const float* nr = rn;
        rn = (l == 0) ? relB : (float*)rc;
        rc = nr;
    }

    k_feats<<<GG, 256, 0, stream>>>(xbfA, rc, rel_labels, feats);
    k_head<<<GG, 256, 0, stream>>>(feats, (const float*)d_in[18],
                                   (const float*)d_in[19], out);
}